// Round 16
// baseline (537.866 us; speedup 1.0000x reference)
//
#include <hip/hip_runtime.h>
#include <hip/hip_bf16.h>

#define DD 1024
#define NHD 64
#define NHEAD 16
#define NE 8
#define NT 4096
#define SS 2048

typedef float v4f __attribute__((ext_vector_type(4)));
typedef short bfx8 __attribute__((ext_vector_type(8)));
typedef float fx4 __attribute__((ext_vector_type(4)));
typedef _Float16 hfx8 __attribute__((ext_vector_type(8)));
typedef unsigned int u32;

// direct global->LDS DMA, 16B per lane; LDS dest = uniform base + lane*16
#define GLOAD16(gp, lp)                                                     \
  __builtin_amdgcn_global_load_lds(                                         \
      (const __attribute__((address_space(1))) u32*)(const u32*)(gp),       \
      (__attribute__((address_space(3))) u32*)(u32*)(lp), 16, 0, 0)

__device__ inline ushort f2bf(float f) {
  union { float f; unsigned u; } x; x.f = f;
  unsigned r = (x.u + 0x7FFFu + ((x.u >> 16) & 1u)) >> 16;
  return (ushort)r;
}
__device__ inline float b2f(ushort u) {
  union { unsigned u; float f; } x; x.u = ((unsigned)u) << 16;
  return x.f;
}
__device__ inline ushort f2h(float f) {
  union { _Float16 h; ushort u; } c; c.h = (_Float16)f; return c.u;
}
__device__ inline float h2f(ushort u) {
  union { ushort u; _Float16 h; } c; c.u = u; return (float)c.h;
}

// ---------------- RMSNorm: one block per row ----------------
__global__ __launch_bounds__(256) void k_rmsnorm(
    const float* __restrict__ x, const float* __restrict__ w,
    float* __restrict__ of32, ushort* __restrict__ obf,
    ushort* __restrict__ oh, ushort* __restrict__ ol) {
  int row = blockIdx.x;
  int tid = threadIdx.x;
  v4f v = *(const v4f*)(x + (size_t)row * DD + tid * 4);
  float ss = v[0]*v[0] + v[1]*v[1] + v[2]*v[2] + v[3]*v[3];
  #pragma unroll
  for (int o = 32; o; o >>= 1) ss += __shfl_down(ss, o);
  __shared__ float red[4];
  if ((tid & 63) == 0) red[tid >> 6] = ss;
  __syncthreads();
  float tot = red[0] + red[1] + red[2] + red[3];
  float sc = rsqrtf(tot * (1.0f / DD) + 1e-5f);
  v4f wv = *(const v4f*)(w + tid * 4);
  v4f o;
  o[0] = v[0]*sc*wv[0]; o[1] = v[1]*sc*wv[1];
  o[2] = v[2]*sc*wv[2]; o[3] = v[3]*sc*wv[3];
  if (of32) *(v4f*)(of32 + (size_t)row * DD + tid * 4) = o;
  if (obf) {
    ushort4 ub;
    ub.x = f2bf(o[0]); ub.y = f2bf(o[1]); ub.z = f2bf(o[2]); ub.w = f2bf(o[3]);
    *(ushort4*)(obf + (size_t)row * DD + tid * 4) = ub;
  }
  if (oh) {
    ushort4 uh, ul;
    float s0 = o[0]*64.f, s1 = o[1]*64.f, s2 = o[2]*64.f, s3 = o[3]*64.f;
    uh.x = f2h(s0); uh.y = f2h(s1); uh.z = f2h(s2); uh.w = f2h(s3);
    ul.x = f2h(s0 - h2f(uh.x)); ul.y = f2h(s1 - h2f(uh.y));
    ul.z = f2h(s2 - h2f(uh.z)); ul.w = f2h(s3 - h2f(uh.w));
    *(ushort4*)(oh + (size_t)row * DD + tid * 4) = uh;
    *(ushort4*)(ol + (size_t)row * DD + tid * 4) = ul;
  }
}

// ---------------- weight transpose + fp16 split (x64): Wt[z][n][k] ----------------
__global__ __launch_bounds__(256) void k_wsplit(
    const float* __restrict__ Wq, const float* __restrict__ Wk,
    const float* __restrict__ Wv, const float* __restrict__ Wo,
    ushort* __restrict__ oh, ushort* __restrict__ ol) {
  __shared__ float tile[32][33];
  int z = blockIdx.z;
  const float* in = (z == 0) ? Wq : (z == 1) ? Wk : (z == 2) ? Wv : Wo;
  size_t zoff = (size_t)z * DD * DD;
  int bx = blockIdx.x * 32, by = blockIdx.y * 32;
  int tx = threadIdx.x & 31, ty = threadIdx.x >> 5;
  #pragma unroll
  for (int i = 0; i < 32; i += 8)
    tile[ty + i][tx] = in[(size_t)(by + ty + i) * DD + bx + tx];
  __syncthreads();
  #pragma unroll
  for (int i = 0; i < 32; i += 8) {
    float vv = tile[tx][ty + i] * 64.f;
    ushort hh = f2h(vv);
    size_t idx = zoff + (size_t)(bx + ty + i) * DD + by + tx;
    oh[idx] = hh;
    ol[idx] = f2h(vv - h2f(hh));
  }
}

// ---------------- split-fp16 MFMA GEMM, 128x128 tile, BK=32, 4 waves ----------------
// Double-buffered direct global->LDS DMA, 2-phase pipeline (issue-ahead).
// MODE 0 (QKV): z selects B slab; epilogue writes q/k hi,lo [bh][s][64] and
//               v^T hi,lo [bh][64][s], all x64-scaled fp16.
// MODE 1 (Wo):  C0 = A@B^T/4096 + resid (fp32).
template<int MODE>
__global__ __launch_bounds__(256) void k_gemm_sp(
    const ushort* __restrict__ Ah, const ushort* __restrict__ Al,
    const ushort* __restrict__ Bth, const ushort* __restrict__ Btl,
    float* __restrict__ C0, const float* __restrict__ resid,
    ushort* __restrict__ o0h, ushort* __restrict__ o0l,
    ushort* __restrict__ o1h, ushort* __restrict__ o1l,
    ushort* __restrict__ o2h, ushort* __restrict__ o2l) {
  const int N = DD, K = DD;
  int z = 0;
  if (MODE == 0) {
    z = blockIdx.z;
    Bth += (size_t)z * DD * DD; Btl += (size_t)z * DD * DD;
  }
  __shared__ ushort lAh[2][128 * 32];
  __shared__ ushort lAl[2][128 * 32];
  __shared__ ushort lBh[2][128 * 32];
  __shared__ ushort lBl[2][128 * 32];
  int tid = threadIdx.x;
  int l = tid & 63, wid = tid >> 6;
  int wm = wid >> 1, wn = wid & 1;
  int m0 = blockIdx.x * 128, n0 = blockIdx.y * 128;
  fx4 zero = {0.f, 0.f, 0.f, 0.f};
  fx4 acc[4][4];
  #pragma unroll
  for (int mt = 0; mt < 4; ++mt)
    #pragma unroll
    for (int nt = 0; nt < 4; ++nt) acc[mt][nt] = zero;
  int sr = tid >> 2;                                 // row 0..63 (half0), +64 (half1)
  int scg = (((l & 3) ^ ((l >> 2) & 3)) << 3);       // pre-swizzled src granule (elems)
  int dofs = wid * 512;                              // wave-uniform LDS dest (ushorts)

#define ISSUE_SP(BUF, KT)                                                        \
  do {                                                                           \
    GLOAD16(Ah  + (size_t)(m0 + sr) * K + (KT) + scg,      lAh[BUF] + dofs);     \
    GLOAD16(Ah  + (size_t)(m0 + sr + 64) * K + (KT) + scg, lAh[BUF] + 2048 + dofs); \
    GLOAD16(Al  + (size_t)(m0 + sr) * K + (KT) + scg,      lAl[BUF] + dofs);     \
    GLOAD16(Al  + (size_t)(m0 + sr + 64) * K + (KT) + scg, lAl[BUF] + 2048 + dofs); \
    GLOAD16(Bth + (size_t)(n0 + sr) * K + (KT) + scg,      lBh[BUF] + dofs);     \
    GLOAD16(Bth + (size_t)(n0 + sr + 64) * K + (KT) + scg, lBh[BUF] + 2048 + dofs); \
    GLOAD16(Btl + (size_t)(n0 + sr) * K + (KT) + scg,      lBl[BUF] + dofs);     \
    GLOAD16(Btl + (size_t)(n0 + sr + 64) * K + (KT) + scg, lBl[BUF] + 2048 + dofs); \
  } while (0)

#define COMP_SP(BUF)                                                             \
  do {                                                                           \
    int kb = (l >> 4) << 4;                                                      \
    hfx8 bfh[4], bfl[4];                                                         \
    _Pragma("unroll")                                                            \
    for (int nt = 0; nt < 4; ++nt) {                                             \
      int row = wn * 64 + nt * 16 + (l & 15);                                    \
      int off = row * 64 + (kb ^ ((row & 3) << 4));                              \
      bfh[nt] = *(hfx8*)((char*)lBh[BUF] + off);                                 \
      bfl[nt] = *(hfx8*)((char*)lBl[BUF] + off);                                 \
    }                                                                            \
    _Pragma("unroll")                                                            \
    for (int mt = 0; mt < 4; ++mt) {                                             \
      int row = wm * 64 + mt * 16 + (l & 15);                                    \
      int off = row * 64 + (kb ^ ((row & 3) << 4));                              \
      hfx8 afh = *(hfx8*)((char*)lAh[BUF] + off);                                \
      hfx8 afl = *(hfx8*)((char*)lAl[BUF] + off);                                \
      _Pragma("unroll")                                                          \
      for (int nt = 0; nt < 4; ++nt) {                                           \
        acc[mt][nt] = __builtin_amdgcn_mfma_f32_16x16x32_f16(afh, bfh[nt], acc[mt][nt], 0, 0, 0); \
        acc[mt][nt] = __builtin_amdgcn_mfma_f32_16x16x32_f16(afl, bfh[nt], acc[mt][nt], 0, 0, 0); \
        acc[mt][nt] = __builtin_amdgcn_mfma_f32_16x16x32_f16(afh, bfl[nt], acc[mt][nt], 0, 0, 0); \
      }                                                                          \
    }                                                                            \
  } while (0)

  ISSUE_SP(0, 0);
  for (int kt = 0; kt < K; kt += 64) {
    __syncthreads();                 // drains buf0 loads; buf1 readers done
    if (kt + 32 < K) ISSUE_SP(1, kt + 32);
    COMP_SP(0);
    __syncthreads();                 // drains buf1 loads; buf0 readers done
    if (kt + 64 < K) ISSUE_SP(0, kt + 64);
    COMP_SP(1);
  }
#undef ISSUE_SP
#undef COMP_SP

  if (MODE == 1) {
    const float SCI = 1.0f / 4096.0f;
    #pragma unroll
    for (int mt = 0; mt < 4; ++mt)
      #pragma unroll
      for (int nt = 0; nt < 4; ++nt)
        #pragma unroll
        for (int r = 0; r < 4; ++r) {
          int row = m0 + wm * 64 + mt * 16 + ((l >> 4) << 2) + r;
          int col = n0 + wn * 64 + nt * 16 + (l & 15);
          size_t idx = (size_t)row * N + col;
          C0[idx] = acc[mt][nt][r] * SCI + resid[idx];
        }
  } else {
    const float SCO = 1.0f / 64.0f;
    ushort* oh = (z == 0) ? o0h : (z == 1) ? o1h : o2h;
    ushort* ol = (z == 0) ? o0l : (z == 1) ? o1l : o2l;
    #pragma unroll
    for (int mt = 0; mt < 4; ++mt)
      #pragma unroll
      for (int nt = 0; nt < 4; ++nt) {
        if (z < 2) {
          #pragma unroll
          for (int r = 0; r < 4; ++r) {
            int t = m0 + wm * 64 + mt * 16 + ((l >> 4) << 2) + r;
            int c = n0 + wn * 64 + nt * 16 + (l & 15);
            float vv = acc[mt][nt][r] * SCO;
            ushort hh = f2h(vv);
            ushort ll = f2h(vv - h2f(hh));
            size_t idx = (size_t)(((t >> 11) << 4) + (c >> 6)) * 131072 +
                         (size_t)(t & 2047) * 64 + (c & 63);
            oh[idx] = hh; ol[idx] = ll;
          }
        } else {
          int t0 = m0 + wm * 64 + mt * 16 + ((l >> 4) << 2);
          int c = n0 + wn * 64 + nt * 16 + (l & 15);
          ushort4 uh, ul;
          float v0 = acc[mt][nt][0] * SCO, v1 = acc[mt][nt][1] * SCO;
          float v2 = acc[mt][nt][2] * SCO, v3 = acc[mt][nt][3] * SCO;
          uh.x = f2h(v0); uh.y = f2h(v1); uh.z = f2h(v2); uh.w = f2h(v3);
          ul.x = f2h(v0 - h2f(uh.x)); ul.y = f2h(v1 - h2f(uh.y));
          ul.z = f2h(v2 - h2f(uh.z)); ul.w = f2h(v3 - h2f(uh.w));
          size_t idx = (size_t)(((t0 >> 11) << 4) + (c >> 6)) * 131072 +
                       (size_t)(c & 63) * 2048 + (t0 & 2047);
          *(ushort4*)(oh + idx) = uh;
          *(ushort4*)(ol + idx) = ul;
        }
      }
  }
}

// ---------------- MFMA flash attention (causal), split-fp16 ----------------
// Pair config + phase-staggered DMA pipeline (V flies under QK, next-K under PV).
// 512 threads = 8 waves; 2 barriers/iter; same 64KB LDS.
__global__ __launch_bounds__(512, 4) void k_attn(
    const ushort* __restrict__ qh, const ushort* __restrict__ ql,
    const ushort* __restrict__ kh, const ushort* __restrict__ kl,
    const ushort* __restrict__ vth, const ushort* __restrict__ vtl,
    ushort* __restrict__ aoh, ushort* __restrict__ aol) {
  __shared__ ushort Ksh[64 * 64];
  __shared__ ushort Ksl[64 * 64];
  __shared__ ushort Vsh[64 * 64];
  __shared__ ushort Vsl[64 * 64];
  __shared__ ushort Psh[2][64 * 64];
  __shared__ ushort Psl[2][64 * 64];
  const float SC = 0.125f / 4096.0f;
  int p = blockIdx.x;            // 0..15
  int bhv = blockIdx.y;          // 0..31
  int b = bhv >> 4, h = bhv & 15;
  int tid = threadIdx.x;
  int l = tid & 63, wid = tid >> 6;   // 8 waves
  int grp = wid >> 2;                  // 0: qi=31-p, 1: qi=p
  int w16 = (wid & 3) * 16;
  int qi = grp ? p : (31 - p);
  int qiMax = 31 - p;
  // staging: buffer = tid>>7 (Kh,Kl,Vh,Vl); 2 waves per buffer
  int bsel = tid >> 7;
  int wh = (tid >> 6) & 1;    // which half of rows (0..31 / 32..63)
  int sr8 = l >> 3;           // row mod 8
  int gsw = (l & 7) ^ sr8;    // pre-swizzled source granule (LDS dest is lane-linear)
  size_t base_k = (size_t)bhv * 131072;
  const ushort* gsrc0;
  int rstr, kstep;
  ushort* lbuf;
  if (bsel == 0)      { gsrc0 = kh  + base_k; rstr = 64;   kstep = 4096; lbuf = Ksh; }
  else if (bsel == 1) { gsrc0 = kl  + base_k; rstr = 64;   kstep = 4096; lbuf = Ksl; }
  else if (bsel == 2) { gsrc0 = vth + base_k; rstr = 2048; kstep = 64;   lbuf = Vsh; }
  else                { gsrc0 = vtl + base_k; rstr = 2048; kstep = 64;   lbuf = Vsl; }
  bool isK = (bsel < 2);
  // Q fragments in registers
  hfx8 qfh[2], qfl[2];
  {
    int qrow = qi * 64 + w16 + (l & 15);
    size_t qo = base_k + (size_t)qrow * 64 + ((l >> 4) << 3);
    qfh[0] = *(const hfx8*)(qh + qo);
    qfh[1] = *(const hfx8*)(qh + qo + 32);
    qfl[0] = *(const hfx8*)(ql + qo);
    qfl[1] = *(const hfx8*)(ql + qo + 32);
  }
  float m[4], lsum[4];
  fx4 oacc[4];
  #pragma unroll
  for (int r = 0; r < 4; ++r) { m[r] = -3e38f; lsum[r] = 0.f; }
  #pragma unroll
  for (int nt = 0; nt < 4; ++nt) oacc[nt] = fx4{0.f, 0.f, 0.f, 0.f};

#define AISSUE(KT)                                                             \
  do {                                                                         \
    const ushort* gs = gsrc0 + (size_t)(KT) * kstep;                           \
    _Pragma("unroll")                                                          \
    for (int i = 0; i < 4; ++i)                                                \
      GLOAD16(gs + (size_t)(wh * 32 + i * 8 + sr8) * rstr + (gsw << 3),        \
              lbuf + (wh * 32 + i * 8) * 64);                                  \
  } while (0)

  if (isK) AISSUE(0);     // prologue: K_0 in flight
  for (int kt = 0; kt <= qiMax; ++kt) {
    __syncthreads();      // (A) drains K_kt (K-waves); PV readers of V_(kt-1) done
    if (!isK) AISSUE(kt); // V_kt flies under QK
    if (kt <= qi) {
      // QK^T: S[16 q][64 k]
      fx4 sacc[4];
      #pragma unroll
      for (int nt = 0; nt < 4; ++nt) sacc[nt] = fx4{0.f, 0.f, 0.f, 0.f};
      #pragma unroll
      for (int c = 0; c < 2; ++c) {
        #pragma unroll
        for (int nt = 0; nt < 4; ++nt) {
          int kcol = nt * 16 + (l & 15);
          int g = (c << 2) | (l >> 4);
          int off = kcol * 64 + ((g ^ (kcol & 7)) << 3);
          hfx8 kbh = *(hfx8*)&Ksh[off];
          hfx8 kbl = *(hfx8*)&Ksl[off];
          sacc[nt] = __builtin_amdgcn_mfma_f32_16x16x32_f16(qfh[c], kbh, sacc[nt], 0, 0, 0);
          sacc[nt] = __builtin_amdgcn_mfma_f32_16x16x32_f16(qfl[c], kbh, sacc[nt], 0, 0, 0);
          sacc[nt] = __builtin_amdgcn_mfma_f32_16x16x32_f16(qfh[c], kbl, sacc[nt], 0, 0, 0);
        }
      }
      if (kt == qi) {
        #pragma unroll
        for (int nt = 0; nt < 4; ++nt)
          #pragma unroll
          for (int r = 0; r < 4; ++r)
            if (nt * 16 + (l & 15) > w16 + ((l >> 4) << 2) + r) sacc[nt][r] = -3e38f;
      }
      __syncthreads();    // (B) drains V_kt; QK readers of K_kt done
      if (isK && kt < qiMax) AISSUE(kt + 1);   // K_(kt+1) flies under softmax+PV
      // online softmax + P hi/lo to LDS (own wave's strip)
      float facr[4];
      #pragma unroll
      for (int r = 0; r < 4; ++r) {
        float mx = fmaxf(fmaxf(sacc[0][r], sacc[1][r]), fmaxf(sacc[2][r], sacc[3][r]));
        mx = fmaxf(mx, __shfl_xor(mx, 1));
        mx = fmaxf(mx, __shfl_xor(mx, 2));
        mx = fmaxf(mx, __shfl_xor(mx, 4));
        mx = fmaxf(mx, __shfl_xor(mx, 8));
        float mn = fmaxf(m[r], mx);
        float fac = __expf(SC * (m[r] - mn));
        m[r] = mn; facr[r] = fac;
        int prow = w16 + ((l >> 4) << 2) + r;
        int rk = (prow & 7);
        float ps = 0.f;
        #pragma unroll
        for (int nt = 0; nt < 4; ++nt) {
          float pv = __expf(SC * (sacc[nt][r] - mn));
          ps += pv;
          ushort ph = f2h(pv);
          ushort pl = f2h(pv - h2f(ph));
          int col = nt * 16 + (l & 15);
          int wa = prow * 64 + (((col >> 3) ^ rk) << 3) + (col & 7);
          Psh[grp][wa] = ph; Psl[grp][wa] = pl;
        }
        ps += __shfl_xor(ps, 1);
        ps += __shfl_xor(ps, 2);
        ps += __shfl_xor(ps, 4);
        ps += __shfl_xor(ps, 8);
        lsum[r] = lsum[r] * fac + ps;
      }
      #pragma unroll
      for (int nt = 0; nt < 4; ++nt)
        #pragma unroll
        for (int r = 0; r < 4; ++r) oacc[nt][r] *= facr[r];
      // PV: O[16 q][64 d] += P @ V   (P written by this wave; lgkmcnt orders)
      #pragma unroll
      for (int c = 0; c < 2; ++c) {
        int prow = w16 + (l & 15);
        int g = (c << 2) | (l >> 4);
        int offp = prow * 64 + ((g ^ (prow & 7)) << 3);
        hfx8 pah = *(hfx8*)&Psh[grp][offp];
        hfx8 pal = *(hfx8*)&Psl[grp][offp];
        #pragma unroll
        for (int nt = 0; nt < 4; ++nt) {
          int d = nt * 16 + (l & 15);
          int offv = d * 64 + ((g ^ (d & 7)) << 3);
          hfx8 vbh = *(hfx8*)&Vsh[offv];
          hfx8 vbl = *(hfx8*)&Vsl[offv];
          oacc[nt] = __builtin_amdgcn_mfma_f32_16x16x32_f16(pah, vbh, oacc[nt], 0, 0, 0);
          oacc[nt] = __builtin_amdgcn_mfma_f32_16x16x32_f16(pal, vbh, oacc[nt], 0, 0, 0);
          oacc[nt] = __builtin_amdgcn_mfma_f32_16x16x32_f16(pah, vbl, oacc[nt], 0, 0, 0);
        }
      }
    } else {
      __syncthreads();    // (B) keep barrier count identical on inactive waves
      if (isK && kt < qiMax) AISSUE(kt + 1);
    }
  }
#undef AISSUE
  // epilogue: out = oacc/lsum (x64-scaled true value), hi/lo fp16
  #pragma unroll
  for (int r = 0; r < 4; ++r) {
    float inv = 1.0f / lsum[r];
    int s = qi * 64 + w16 + ((l >> 4) << 2) + r;
    #pragma unroll
    for (int nt = 0; nt < 4; ++nt) {
      int d = nt * 16 + (l & 15);
      float ot = oacc[nt][r] * inv;
      ushort hh = f2h(ot);
      ushort ll = f2h(ot - h2f(hh));
      size_t idx = ((size_t)b * 2048 + s) * 1024 + h * 64 + d;
      aoh[idx] = hh; aol[idx] = ll;
    }
  }
}

// ---------------- transpose + cast fp32 -> bf16 (z: 0-7 = W1, 8-15 = W2) ----------------
__global__ __launch_bounds__(256) void k_tcast(
    const float* __restrict__ inA, const float* __restrict__ inB,
    ushort* __restrict__ out, int R, int C) {
  __shared__ float tile[32][33];
  int z = blockIdx.z;
  const float* in = (z < 8) ? (inA + (size_t)z * R * C) : (inB + (size_t)(z - 8) * R * C);
  size_t zoff = (size_t)z * R * C;
  int bx = blockIdx.x * 32, by = blockIdx.y * 32;
  int tx = threadIdx.x & 31, ty = threadIdx.x >> 5;
  #pragma unroll
  for (int i = 0; i < 32; i += 8)
    tile[ty + i][tx] = in[(size_t)(by + ty + i) * C + bx + tx];
  __syncthreads();
  #pragma unroll
  for (int i = 0; i < 32; i += 8)
    out[zoff + (size_t)(bx + ty + i) * R + by + tx] = f2bf(tile[tx][ty + i]);
}

// ---------------- gating: one wave per token ----------------
__global__ __launch_bounds__(256) void k_gate(
    const float* __restrict__ post, const float* __restrict__ gw,
    float* __restrict__ w12, float* __restrict__ probs, int* __restrict__ sel) {
  int t = blockIdx.x * 4 + (threadIdx.x >> 6);
  int lane = threadIdx.x & 63;
  float acc[8] = {};
  const float* xr = post + (size_t)t * DD;
  for (int it = 0; it < 16; ++it) {
    int d = it * 64 + lane;
    float xd = xr[d];
    v4f g0 = *(const v4f*)(gw + d * 8);
    v4f g1 = *(const v4f*)(gw + d * 8 + 4);
    acc[0] = fmaf(xd, g0[0], acc[0]); acc[1] = fmaf(xd, g0[1], acc[1]);
    acc[2] = fmaf(xd, g0[2], acc[2]); acc[3] = fmaf(xd, g0[3], acc[3]);
    acc[4] = fmaf(xd, g1[0], acc[4]); acc[5] = fmaf(xd, g1[1], acc[5]);
    acc[6] = fmaf(xd, g1[2], acc[6]); acc[7] = fmaf(xd, g1[3], acc[7]);
  }
  #pragma unroll
  for (int e = 0; e < 8; ++e) {
    float s = acc[e];
    #pragma unroll
    for (int o = 32; o; o >>= 1) s += __shfl_down(s, o);
    acc[e] = s;
  }
  if (lane == 0) {
    float mx = acc[0];
    #pragma unroll
    for (int e = 1; e < 8; ++e) mx = fmaxf(mx, acc[e]);
    float p[8], sum = 0.f;
    #pragma unroll
    for (int e = 0; e < 8; ++e) { p[e] = __expf(acc[e] - mx); sum += p[e]; }
    float inv = 1.f / sum;
    #pragma unroll
    for (int e = 0; e < 8; ++e) p[e] *= inv;
    int e1 = 0; float l1 = acc[0];
    for (int e = 1; e < 8; ++e) if (acc[e] > l1) { l1 = acc[e]; e1 = e; }
    int e2 = -1; float l2 = -1e38f;
    for (int e = 0; e < 8; ++e) if (e != e1 && acc[e] > l2) { l2 = acc[e]; e2 = e; }
    float v1 = p[e1], v2 = p[e2];
    float s2 = 1.f / (v1 + v2);
    for (int e = 0; e < 8; ++e) probs[t * 8 + e] = p[e];
    w12[2 * t] = v1 * s2;
    w12[2 * t + 1] = v2 * s2;
    sel[t] = e1 * 8 + e2;
  }
}

// ---------------- routing: histogram + offsets (1 block) ----------------
__global__ __launch_bounds__(256) void k_count(
    const int* __restrict__ sel, int* __restrict__ offs) {
  __shared__ int h[8];
  int tid = threadIdx.x;
  if (tid < 8) h[tid] = 0;
  __syncthreads();
  for (int t = tid; t < NT; t += 256) {
    int s = sel[t];
    atomicAdd(&h[s >> 3], 1);
    atomicAdd(&h[s & 7], 1);
  }
  __syncthreads();
  if (tid == 0) {
    int run = 0;
    for (int e = 0; e < 8; ++e) { offs[e] = run; run += h[e]; }
    offs[8] = run;
  }
}

// ---------------- routing: stable placement (block e = expert e) ----------------
__global__ __launch_bounds__(256) void k_place(
    const int* __restrict__ sel, const int* __restrict__ offs,
    int* __restrict__ list, int* __restrict__ inv) {
  int e = blockIdx.x;
  int tid = threadIdx.x;
  __shared__ int a[256];
  int base = tid * 16;
  int c = 0;
  #pragma unroll
  for (int i = 0; i < 16; ++i) {
    int s = sel[base + i];
    c += ((s >> 3) == e) + ((s & 7) == e);
  }
  a[tid] = c;
  __syncthreads();
  for (int st = 1; st < 256; st <<= 1) {
    int tv = (tid >= st) ? a[tid - st] : 0;
    __syncthreads();
    a[tid] += tv;
    __syncthreads();
  }
  int slot = offs[e] + a[tid] - c;
  for (int i = 0; i < 16; ++i) {
    int t = base + i;
    int s = sel[t];
    if ((s >> 3) == e) { list[slot] = t; inv[2 * t] = slot; ++slot; }
    if ((s & 7) == e)  { list[slot] = t; inv[2 * t + 1] = slot; ++slot; }
  }
}

// ---------------- sparse expert GEMM: bf16 MFMA, 128x128 tile, z = expert ----------------
// Double-buffered direct global->LDS DMA, 2-phase pipeline.
template<int MODE>
__global__ __launch_bounds__(256) void k_moe_gemm(
    const ushort* __restrict__ A, const ushort* __restrict__ BtAll,
    ushort* __restrict__ hb, ushort* __restrict__ ob,
    const int* __restrict__ list, const int* __restrict__ offs,
    int N, int K) {
  int e = blockIdx.z;
  const ushort* Bt = BtAll + (size_t)e * DD * DD;
  int off = offs[e];
  int Me = offs[e + 1] - off;
  int m0 = blockIdx.x * 128;
  if (m0 >= Me) return;
  __shared__ ushort lA[2][128 * 32];
  __shared__ ushort lB[2][128 * 32];
  int tid = threadIdx.x;
  int l = tid & 63, wid = tid >> 6;
  int wm = wid >> 1, wn = wid & 1;
  int n0 = blockIdx.y * 128;
  fx4 zero = {0.f, 0.f, 0.f, 0.f};
  fx4 acc[4][4];
  #pragma unroll
  for (int mt = 0; mt < 4; ++mt)
    #pragma unroll
    for (int nt = 0; nt < 4; ++nt) acc[mt][nt] = zero;
  int sr = tid >> 2;
  int scg = (((l & 3) ^ ((l >> 2) & 3)) << 3);
  int dofs = wid * 512;
  int cr0 = m0 + sr;      if (cr0 > Me - 1) cr0 = Me - 1;
  int cr1 = m0 + sr + 64; if (cr1 > Me - 1) cr1 = Me - 1;
  size_t ar0, ar1;
  if (MODE == 0) { ar0 = (size_t)list[off + cr0]; ar1 = (size_t)list[off + cr1]; }
  else           { ar0 = (size_t)(off + cr0);     ar1 = (size_t)(off + cr1); }

#define ISSUE_MOE(BUF, KT)                                                       \
  do {                                                                           \
    GLOAD16(A  + ar0 * K + (KT) + scg,                    lA[BUF] + dofs);       \
    GLOAD16(A  + ar1 * K + (KT) + scg,                    lA[BUF] + 2048 + dofs);\
    GLOAD16(Bt + (size_t)(n0 + sr) * K + (KT) + scg,      lB[BUF] + dofs);       \
    GLOAD16(Bt + (size_t)(n0 + sr + 64) * K + (KT) + scg, lB[BUF] + 2048 + dofs);\
  } while (0)

#define COMP_MOE(BUF)                                                            \
  do {                                                                           \
    int kb = (l >> 4) << 4;                                                      \
    bfx8 bfr[4];                                                                 \
    _Pragma("unroll")                                                            \
    for (int nt = 0; nt < 4; ++nt) {                                             \
      int row = wn * 64 + nt * 16 + (l & 15);                                    \
      bfr[nt] = *(bfx8*)((char*)lB[BUF] + row * 64 + (kb ^ ((row & 3) << 4)));   \
    }                                                                            \
    _Pragma("unroll")                                                            \
    for (int mt = 0; mt < 4; ++mt) {                                             \
      int row = wm * 64 + mt * 16 + (l & 15);                                    \
      bfx8 af = *(bfx8*)((char*)lA[BUF] + row * 64 + (kb ^ ((row & 3) << 4)));   \
      _Pragma("unroll")                                                          \
      for (int nt = 0; nt < 4; ++nt)                                             \
        acc[mt][nt] = __builtin_amdgcn_mfma_f32_16x16x32_bf16(af, bfr[nt], acc[mt][nt], 0, 0, 0); \
    }                                                                            \
  } while (0)

  ISSUE_MOE(0, 0);
  for (int kt = 0; kt < K; kt += 64) {
    __syncthreads();
    if (kt + 32 < K) ISSUE_MOE(1, kt + 32);
    COMP_MOE(0);
    __syncthreads();
    if (kt + 64 < K) ISSUE_MOE(0, kt + 64);
    COMP_MOE(1);
  }
#undef ISSUE_MOE
#undef COMP_MOE

  #pragma unroll
  for (int mt = 0; mt < 4; ++mt)
    #pragma unroll
    for (int nt = 0; nt < 4; ++nt)
      #pragma unroll
      for (int r = 0; r < 4; ++r) {
        int rowt = wm * 64 + mt * 16 + ((l >> 4) << 2) + r;
        if (m0 + rowt < Me) {
          int col = n0 + wn * 64 + nt * 16 + (l & 15);
          float vv = acc[mt][nt][r];
          size_t idx = (size_t)(off + m0 + rowt) * N + col;
          if (MODE == 0) hb[idx] = f2bf(fmaxf(vv, 0.f));
          else           ob[idx] = f2bf(vv);
        }
      }
}

// ---------------- combine: out = psum + w1*o[inv1] + w2*o[inv2] (o in bf16) ----------------
__global__ __launch_bounds__(256) void k_combine(
    const float* __restrict__ psum, const ushort* __restrict__ ob,
    const int* __restrict__ inv, const float* __restrict__ w12,
    float* __restrict__ out) {
  int t = blockIdx.x;
  int d = threadIdx.x * 4;
  v4f a = *(const v4f*)(psum + (size_t)t * DD + d);
  ushort4 u1 = *(const ushort4*)(ob + (size_t)inv[2 * t] * DD + d);
  ushort4 u2 = *(const ushort4*)(ob + (size_t)inv[2 * t + 1] * DD + d);
  float w1 = w12[2 * t], w2 = w12[2 * t + 1];
  v4f r;
  r[0] = a[0] + w1 * b2f(u1.x) + w2 * b2f(u2.x);
  r[1] = a[1] + w1 * b2f(u1.y) + w2 * b2f(u2.y);
  r[2] = a[2] + w1 * b2f(u1.z) + w2 * b2f(u2.z);
  r[3] = a[3] + w1 * b2f(u1.w) + w2 * b2f(u2.w);
  *(v4f*)(out + (size_t)t * DD + d) = r;
}

// ---------------- aux loss: deterministic single-block reduce ----------------
__global__ __launch_bounds__(256) void k_aux(
    const float* __restrict__ probs, const int* __restrict__ sel,
    float* __restrict__ auxout) {
  int tid = threadIdx.x;
  float ps[8] = {}, cs[8] = {};
  for (int t = tid; t < NT; t += 256) {
    #pragma unroll
    for (int e = 0; e < 8; ++e) ps[e] += probs[t * 8 + e];
    int s = sel[t];
    cs[s >> 3] += 1.f; cs[s & 7] += 1.f;
  }
  __shared__ float red[4];
  __shared__ float tot[16];
  #pragma unroll
  for (int vv = 0; vv < 16; ++vv) {
    float s = (vv < 8) ? ps[vv] : cs[vv - 8];
    #pragma unroll
    for (int o = 32; o; o >>= 1) s += __shfl_down(s, o);
    __syncthreads();
    if ((tid & 63) == 0) red[tid >> 6] = s;
    __syncthreads();
    if (tid == 0) tot[vv] = red[0] + red[1] + red[2] + red[3];
  }
  __syncthreads();
  if (tid == 0) {
    float aux = 0.f;
    for (int e = 0; e < 8; ++e)
      aux += (tot[8 + e] * (1.f / NT)) * (tot[e] * (1.f / NT));
    auxout[0] = 8.f * aux;
  }
}

extern "C" void kernel_launch(void* const* d_in, const int* in_sizes, int n_in,
                              void* d_out, int out_size, void* d_ws, size_t ws_size,
                              hipStream_t stream) {
  (void)in_sizes; (void)n_in; (void)out_size; (void)ws_size;
  const float* x     = (const float*)d_in[0];
  const float* wpre  = (const float*)d_in[1];
  const float* wpost = (const float*)d_in[2];
  const float* Wq    = (const float*)d_in[3];
  const float* Wk    = (const float*)d_in[4];
  const float* Wv    = (const float*)d_in[5];
  const float* Wo    = (const float*)d_in[6];
  const float* gw    = (const float*)d_in[7];
  const float* W1    = (const float*)d_in[8];
  const float* W2    = (const float*)d_in[9];
  float* out = (float*)d_out;
  char* ws = (char*)d_ws;
  const size_t MB = 1ull << 20;
  // phase-overlaid workspace map (112MB + tail)
  ushort* preh  = (ushort*)(ws + 0 * MB);   // 8MB  -> aoh -> hb(16MB @0)
  ushort* prel  = (ushort*)(ws + 8 * MB);   // 8MB  -> aol
  ushort* qh    = (ushort*)(ws + 16 * MB);  // 8MB  -> postf (16MB @16)
  ushort* ql    = (ushort*)(ws + 24 * MB);  // 8MB
  ushort* kh    = (ushort*)(ws + 32 * MB);  // 8MB  -> postb (8MB @32)
  ushort* kl    = (ushort*)(ws + 40 * MB);  // 8MB  -> ob (16MB @40)
  ushort* vth   = (ushort*)(ws + 48 * MB);  // 8MB
  ushort* vtl   = (ushort*)(ws + 56 * MB);  // 8MB
  float*  psum  = (float*)(ws + 64 * MB);   // 16MB (live to end)
  ushort* Wt4h  = (ushort*)(ws + 80 * MB);  // 8MB  -> W1t (16MB @80)
  ushort* Wt4l  = (ushort*)(ws + 88 * MB);  // 8MB
  ushort* W2t   = (ushort*)(ws + 96 * MB);  // 16MB
  ushort* W1t   = (ushort*)(ws + 80 * MB);
  ushort* aoh   = preh;
  ushort* aol   = prel;
  float*  postf = (float*)(ws + 16 * MB);
  ushort* postb = (ushort*)(ws + 32 * MB);
  ushort* hb    = (ushort*)(ws + 0 * MB);
  ushort* ob    = (ushort*)(ws + 40 * MB);
  float*  probs = (float*)(ws + 112 * MB);
  int*    sel   = (int*)(ws + 112 * MB + (128u << 10));
  float*  w12   = (float*)(ws + 112 * MB + (160u << 10));
  int*    list  = (int*)(ws + 112 * MB + (192u << 10));
  int*    offs  = (int*)(ws + 112 * MB + (224u << 10));
  int*    inv   = (int*)(ws + 112 * MB + (256u << 10));

  // pre-norm -> fp16 hi/lo (x64)
  k_rmsnorm<<<NT, 256, 0, stream>>>(x, wpre, nullptr, nullptr, preh, prel);
  // weight transpose+split for Wq/Wk/Wv/Wo
  k_wsplit<<<dim3(32, 32, 4), 256, 0, stream>>>(Wq, Wk, Wv, Wo, Wt4h, Wt4l);
  // QKV via split-fp16 MFMA (128x128 tile, double-buffered DMA pipeline)
  k_gemm_sp<0><<<dim3(32, 8, 3), 256, 0, stream>>>(
      preh, prel, Wt4h, Wt4l, nullptr, nullptr, qh, ql, kh, kl, vth, vtl);
  // MFMA flash attention (pair config + phase-staggered DMA) -> hi/lo fp16
  k_attn<<<dim3(16, 32), 512, 0, stream>>>(qh, ql, kh, kl, vth, vtl, aoh, aol);
  // Wo + residual -> post_sum (split-fp16 MFMA, double-buffered DMA pipeline)
  k_gemm_sp<1><<<dim3(32, 8, 1), 256, 0, stream>>>(
      aoh, aol, Wt4h + (size_t)3 * DD * DD, Wt4l + (size_t)3 * DD * DD,
      psum, x, nullptr, nullptr, nullptr, nullptr, nullptr, nullptr);
  // post-norm: fp32 (gating) + bf16 (MoE A operand)
  k_rmsnorm<<<NT, 256, 0, stream>>>(psum, wpost, postf, postb, nullptr, nullptr);
  // expert weights -> bf16 transposed (both W1 and W2 in one dispatch)
  k_tcast<<<dim3(32, 32, 16), 256, 0, stream>>>(W1, W2, W1t, DD, DD);
  // gating (fp32, exact top-k path)
  k_gate<<<NT / 4, 256, 0, stream>>>(postf, gw, w12, probs, sel);
  // routing
  k_count<<<1, 256, 0, stream>>>(sel, offs);
  k_place<<<8, 256, 0, stream>>>(sel, offs, list, inv);
  // sparse MoE: all experts in one dispatch per stage (z = expert), 128x128 tiles
  k_moe_gemm<0><<<dim3(32, 8, 8), 256, 0, stream>>>(
      postb, W1t, hb, nullptr, list, offs, DD, DD);
  k_moe_gemm<1><<<dim3(32, 8, 8), 256, 0, stream>>>(
      hb, W2t, nullptr, ob, list, offs, DD, DD);
  // combine + aux
  k_combine<<<NT, 256, 0, stream>>>(psum, ob, inv, w12, out);
  k_aux<<<1, 256, 0, stream>>>(probs, sel, out + 4194304);
}

// Round 17
// 506.711 us; speedup vs baseline: 1.0615x; 1.0615x over previous
//
#include <hip/hip_runtime.h>
#include <hip/hip_bf16.h>

#define DD 1024
#define NHD 64
#define NHEAD 16
#define NE 8
#define NT 4096
#define SS 2048

typedef float v4f __attribute__((ext_vector_type(4)));
typedef short bfx8 __attribute__((ext_vector_type(8)));
typedef float fx4 __attribute__((ext_vector_type(4)));
typedef _Float16 hfx8 __attribute__((ext_vector_type(8)));
typedef unsigned int u32;

// direct global->LDS DMA, 16B per lane; LDS dest = uniform base + lane*16
#define GLOAD16(gp, lp)                                                     \
  __builtin_amdgcn_global_load_lds(                                         \
      (const __attribute__((address_space(1))) u32*)(const u32*)(gp),       \
      (__attribute__((address_space(3))) u32*)(u32*)(lp), 16, 0, 0)

__device__ inline ushort f2bf(float f) {
  union { float f; unsigned u; } x; x.f = f;
  unsigned r = (x.u + 0x7FFFu + ((x.u >> 16) & 1u)) >> 16;
  return (ushort)r;
}
__device__ inline float b2f(ushort u) {
  union { unsigned u; float f; } x; x.u = ((unsigned)u) << 16;
  return x.f;
}
__device__ inline ushort f2h(float f) {
  union { _Float16 h; ushort u; } c; c.h = (_Float16)f; return c.u;
}
__device__ inline float h2f(ushort u) {
  union { ushort u; _Float16 h; } c; c.u = u; return (float)c.h;
}

// ---------------- RMSNorm: one block per row ----------------
__global__ __launch_bounds__(256) void k_rmsnorm(
    const float* __restrict__ x, const float* __restrict__ w,
    float* __restrict__ of32, ushort* __restrict__ obf,
    ushort* __restrict__ oh, ushort* __restrict__ ol) {
  int row = blockIdx.x;
  int tid = threadIdx.x;
  v4f v = *(const v4f*)(x + (size_t)row * DD + tid * 4);
  float ss = v[0]*v[0] + v[1]*v[1] + v[2]*v[2] + v[3]*v[3];
  #pragma unroll
  for (int o = 32; o; o >>= 1) ss += __shfl_down(ss, o);
  __shared__ float red[4];
  if ((tid & 63) == 0) red[tid >> 6] = ss;
  __syncthreads();
  float tot = red[0] + red[1] + red[2] + red[3];
  float sc = rsqrtf(tot * (1.0f / DD) + 1e-5f);
  v4f wv = *(const v4f*)(w + tid * 4);
  v4f o;
  o[0] = v[0]*sc*wv[0]; o[1] = v[1]*sc*wv[1];
  o[2] = v[2]*sc*wv[2]; o[3] = v[3]*sc*wv[3];
  if (of32) *(v4f*)(of32 + (size_t)row * DD + tid * 4) = o;
  if (obf) {
    ushort4 ub;
    ub.x = f2bf(o[0]); ub.y = f2bf(o[1]); ub.z = f2bf(o[2]); ub.w = f2bf(o[3]);
    *(ushort4*)(obf + (size_t)row * DD + tid * 4) = ub;
  }
  if (oh) {
    ushort4 uh, ul;
    float s0 = o[0]*64.f, s1 = o[1]*64.f, s2 = o[2]*64.f, s3 = o[3]*64.f;
    uh.x = f2h(s0); uh.y = f2h(s1); uh.z = f2h(s2); uh.w = f2h(s3);
    ul.x = f2h(s0 - h2f(uh.x)); ul.y = f2h(s1 - h2f(uh.y));
    ul.z = f2h(s2 - h2f(uh.z)); ul.w = f2h(s3 - h2f(uh.w));
    *(ushort4*)(oh + (size_t)row * DD + tid * 4) = uh;
    *(ushort4*)(ol + (size_t)row * DD + tid * 4) = ul;
  }
}

// ---------------- weight transpose + fp16 split (x64): Wt[z][n][k] ----------------
__global__ __launch_bounds__(256) void k_wsplit(
    const float* __restrict__ Wq, const float* __restrict__ Wk,
    const float* __restrict__ Wv, const float* __restrict__ Wo,
    ushort* __restrict__ oh, ushort* __restrict__ ol) {
  __shared__ float tile[32][33];
  int z = blockIdx.z;
  const float* in = (z == 0) ? Wq : (z == 1) ? Wk : (z == 2) ? Wv : Wo;
  size_t zoff = (size_t)z * DD * DD;
  int bx = blockIdx.x * 32, by = blockIdx.y * 32;
  int tx = threadIdx.x & 31, ty = threadIdx.x >> 5;
  #pragma unroll
  for (int i = 0; i < 32; i += 8)
    tile[ty + i][tx] = in[(size_t)(by + ty + i) * DD + bx + tx];
  __syncthreads();
  #pragma unroll
  for (int i = 0; i < 32; i += 8) {
    float vv = tile[tx][ty + i] * 64.f;
    ushort hh = f2h(vv);
    size_t idx = zoff + (size_t)(bx + ty + i) * DD + by + tx;
    oh[idx] = hh;
    ol[idx] = f2h(vv - h2f(hh));
  }
}

// ---------------- split-fp16 MFMA GEMM, 128x128 tile, BK=32, 4 waves ----------------
// Double-buffered direct global->LDS DMA, 2-phase pipeline (issue-ahead).
template<int MODE>
__global__ __launch_bounds__(256) void k_gemm_sp(
    const ushort* __restrict__ Ah, const ushort* __restrict__ Al,
    const ushort* __restrict__ Bth, const ushort* __restrict__ Btl,
    float* __restrict__ C0, const float* __restrict__ resid,
    ushort* __restrict__ o0h, ushort* __restrict__ o0l,
    ushort* __restrict__ o1h, ushort* __restrict__ o1l,
    ushort* __restrict__ o2h, ushort* __restrict__ o2l) {
  const int N = DD, K = DD;
  int z = 0;
  if (MODE == 0) {
    z = blockIdx.z;
    Bth += (size_t)z * DD * DD; Btl += (size_t)z * DD * DD;
  }
  __shared__ ushort lAh[2][128 * 32];
  __shared__ ushort lAl[2][128 * 32];
  __shared__ ushort lBh[2][128 * 32];
  __shared__ ushort lBl[2][128 * 32];
  int tid = threadIdx.x;
  int l = tid & 63, wid = tid >> 6;
  int wm = wid >> 1, wn = wid & 1;
  int m0 = blockIdx.x * 128, n0 = blockIdx.y * 128;
  fx4 zero = {0.f, 0.f, 0.f, 0.f};
  fx4 acc[4][4];
  #pragma unroll
  for (int mt = 0; mt < 4; ++mt)
    #pragma unroll
    for (int nt = 0; nt < 4; ++nt) acc[mt][nt] = zero;
  int sr = tid >> 2;
  int scg = (((l & 3) ^ ((l >> 2) & 3)) << 3);
  int dofs = wid * 512;

#define ISSUE_SP(BUF, KT)                                                        \
  do {                                                                           \
    GLOAD16(Ah  + (size_t)(m0 + sr) * K + (KT) + scg,      lAh[BUF] + dofs);     \
    GLOAD16(Ah  + (size_t)(m0 + sr + 64) * K + (KT) + scg, lAh[BUF] + 2048 + dofs); \
    GLOAD16(Al  + (size_t)(m0 + sr) * K + (KT) + scg,      lAl[BUF] + dofs);     \
    GLOAD16(Al  + (size_t)(m0 + sr + 64) * K + (KT) + scg, lAl[BUF] + 2048 + dofs); \
    GLOAD16(Bth + (size_t)(n0 + sr) * K + (KT) + scg,      lBh[BUF] + dofs);     \
    GLOAD16(Bth + (size_t)(n0 + sr + 64) * K + (KT) + scg, lBh[BUF] + 2048 + dofs); \
    GLOAD16(Btl + (size_t)(n0 + sr) * K + (KT) + scg,      lBl[BUF] + dofs);     \
    GLOAD16(Btl + (size_t)(n0 + sr + 64) * K + (KT) + scg, lBl[BUF] + 2048 + dofs); \
  } while (0)

#define COMP_SP(BUF)                                                             \
  do {                                                                           \
    int kb = (l >> 4) << 4;                                                      \
    hfx8 bfh[4], bfl[4];                                                         \
    _Pragma("unroll")                                                            \
    for (int nt = 0; nt < 4; ++nt) {                                             \
      int row = wn * 64 + nt * 16 + (l & 15);                                    \
      int off = row * 64 + (kb ^ ((row & 3) << 4));                              \
      bfh[nt] = *(hfx8*)((char*)lBh[BUF] + off);                                 \
      bfl[nt] = *(hfx8*)((char*)lBl[BUF] + off);                                 \
    }                                                                            \
    _Pragma("unroll")                                                            \
    for (int mt = 0; mt < 4; ++mt) {                                             \
      int row = wm * 64 + mt * 16 + (l & 15);                                    \
      int off = row * 64 + (kb ^ ((row & 3) << 4));                              \
      hfx8 afh = *(hfx8*)((char*)lAh[BUF] + off);                                \
      hfx8 afl = *(hfx8*)((char*)lAl[BUF] + off);                                \
      _Pragma("unroll")                                                          \
      for (int nt = 0; nt < 4; ++nt) {                                           \
        acc[mt][nt] = __builtin_amdgcn_mfma_f32_16x16x32_f16(afh, bfh[nt], acc[mt][nt], 0, 0, 0); \
        acc[mt][nt] = __builtin_amdgcn_mfma_f32_16x16x32_f16(afl, bfh[nt], acc[mt][nt], 0, 0, 0); \
        acc[mt][nt] = __builtin_amdgcn_mfma_f32_16x16x32_f16(afh, bfl[nt], acc[mt][nt], 0, 0, 0); \
      }                                                                          \
    }                                                                            \
  } while (0)

  ISSUE_SP(0, 0);
  for (int kt = 0; kt < K; kt += 64) {
    __syncthreads();
    if (kt + 32 < K) ISSUE_SP(1, kt + 32);
    COMP_SP(0);
    __syncthreads();
    if (kt + 64 < K) ISSUE_SP(0, kt + 64);
    COMP_SP(1);
  }
#undef ISSUE_SP
#undef COMP_SP

  if (MODE == 1) {
    const float SCI = 1.0f / 4096.0f;
    #pragma unroll
    for (int mt = 0; mt < 4; ++mt)
      #pragma unroll
      for (int nt = 0; nt < 4; ++nt)
        #pragma unroll
        for (int r = 0; r < 4; ++r) {
          int row = m0 + wm * 64 + mt * 16 + ((l >> 4) << 2) + r;
          int col = n0 + wn * 64 + nt * 16 + (l & 15);
          size_t idx = (size_t)row * N + col;
          C0[idx] = acc[mt][nt][r] * SCI + resid[idx];
        }
  } else {
    const float SCO = 1.0f / 64.0f;
    ushort* oh = (z == 0) ? o0h : (z == 1) ? o1h : o2h;
    ushort* ol = (z == 0) ? o0l : (z == 1) ? o1l : o2l;
    #pragma unroll
    for (int mt = 0; mt < 4; ++mt)
      #pragma unroll
      for (int nt = 0; nt < 4; ++nt) {
        if (z < 2) {
          #pragma unroll
          for (int r = 0; r < 4; ++r) {
            int t = m0 + wm * 64 + mt * 16 + ((l >> 4) << 2) + r;
            int c = n0 + wn * 64 + nt * 16 + (l & 15);
            float vv = acc[mt][nt][r] * SCO;
            ushort hh = f2h(vv);
            ushort ll = f2h(vv - h2f(hh));
            size_t idx = (size_t)(((t >> 11) << 4) + (c >> 6)) * 131072 +
                         (size_t)(t & 2047) * 64 + (c & 63);
            oh[idx] = hh; ol[idx] = ll;
          }
        } else {
          int t0 = m0 + wm * 64 + mt * 16 + ((l >> 4) << 2);
          int c = n0 + wn * 64 + nt * 16 + (l & 15);
          ushort4 uh, ul;
          float v0 = acc[mt][nt][0] * SCO, v1 = acc[mt][nt][1] * SCO;
          float v2 = acc[mt][nt][2] * SCO, v3 = acc[mt][nt][3] * SCO;
          uh.x = f2h(v0); uh.y = f2h(v1); uh.z = f2h(v2); uh.w = f2h(v3);
          ul.x = f2h(v0 - h2f(uh.x)); ul.y = f2h(v1 - h2f(uh.y));
          ul.z = f2h(v2 - h2f(uh.z)); ul.w = f2h(v3 - h2f(uh.w));
          size_t idx = (size_t)(((t0 >> 11) << 4) + (c >> 6)) * 131072 +
                       (size_t)(c & 63) * 2048 + (t0 & 2047);
          *(ushort4*)(oh + idx) = uh;
          *(ushort4*)(ol + idx) = ul;
        }
      }
  }
}

// ---------------- MFMA flash attention (causal), split-fp16 ----------------
// R13-proven body; flat 512-block grid with XCD-clustering: xcd = f&7 hosts
// bhv in {4*xcd..4*xcd+3} (4MB K/V working set = one L2). 8 waves, pair scheme.
__global__ __launch_bounds__(512, 4) void k_attn(
    const ushort* __restrict__ qh, const ushort* __restrict__ ql,
    const ushort* __restrict__ kh, const ushort* __restrict__ kl,
    const ushort* __restrict__ vth, const ushort* __restrict__ vtl,
    ushort* __restrict__ aoh, ushort* __restrict__ aol) {
  __shared__ ushort Ksh[64 * 64];
  __shared__ ushort Ksl[64 * 64];
  __shared__ ushort Vsh[64 * 64];
  __shared__ ushort Vsl[64 * 64];
  __shared__ ushort Psh[2][64 * 64];
  __shared__ ushort Psl[2][64 * 64];
  const float SC = 0.125f / 4096.0f;
  int f = blockIdx.x;                  // 0..511, XCD-clustered mapping
  int idx8 = f >> 3;                   // 0..63
  int bhv = ((f & 7) << 2) | (idx8 >> 4);   // 4 bh per XCD
  int p = idx8 & 15;                   // 0..15
  int b = bhv >> 4, h = bhv & 15;
  int tid = threadIdx.x;
  int l = tid & 63, wid = tid >> 6;   // 8 waves
  int grp = wid >> 2;                  // 0: qi=31-p, 1: qi=p
  int w16 = (wid & 3) * 16;
  int qi = grp ? p : (31 - p);
  int qiMax = 31 - p;
  // staging: buffer = tid>>7 (Kh,Kl,Vh,Vl); 2 waves per buffer
  int bsel = tid >> 7;
  int wh = (tid >> 6) & 1;    // which half of rows (0..31 / 32..63)
  int sr8 = l >> 3;           // row mod 8
  int gsw = (l & 7) ^ sr8;    // pre-swizzled source granule (LDS dest is lane-linear)
  size_t base_k = (size_t)bhv * 131072;
  const ushort* gsrc0;
  int rstr, kstep;
  ushort* lbuf;
  if (bsel == 0)      { gsrc0 = kh  + base_k; rstr = 64;   kstep = 4096; lbuf = Ksh; }
  else if (bsel == 1) { gsrc0 = kl  + base_k; rstr = 64;   kstep = 4096; lbuf = Ksl; }
  else if (bsel == 2) { gsrc0 = vth + base_k; rstr = 2048; kstep = 64;   lbuf = Vsh; }
  else                { gsrc0 = vtl + base_k; rstr = 2048; kstep = 64;   lbuf = Vsl; }
  // Q fragments in registers
  hfx8 qfh[2], qfl[2];
  {
    int qrow = qi * 64 + w16 + (l & 15);
    size_t qo = base_k + (size_t)qrow * 64 + ((l >> 4) << 3);
    qfh[0] = *(const hfx8*)(qh + qo);
    qfh[1] = *(const hfx8*)(qh + qo + 32);
    qfl[0] = *(const hfx8*)(ql + qo);
    qfl[1] = *(const hfx8*)(ql + qo + 32);
  }
  float m[4], lsum[4];
  fx4 oacc[4];
  #pragma unroll
  for (int r = 0; r < 4; ++r) { m[r] = -3e38f; lsum[r] = 0.f; }
  #pragma unroll
  for (int nt = 0; nt < 4; ++nt) oacc[nt] = fx4{0.f, 0.f, 0.f, 0.f};
  for (int kt = 0; kt <= qiMax; ++kt) {
    __syncthreads();   // (A) prev-iter LDS readers done; LDS free
    {
      const ushort* gs = gsrc0 + (size_t)kt * kstep;
      #pragma unroll
      for (int i = 0; i < 4; ++i)
        GLOAD16(gs + (size_t)(wh * 32 + i * 8 + sr8) * rstr + (gsw << 3),
                lbuf + (wh * 32 + i * 8) * 64);
    }
    __syncthreads();   // (B) DMA drained; tiles visible
    if (kt <= qi) {
      // QK^T: S[16 q][64 k]
      fx4 sacc[4];
      #pragma unroll
      for (int nt = 0; nt < 4; ++nt) sacc[nt] = fx4{0.f, 0.f, 0.f, 0.f};
      #pragma unroll
      for (int c = 0; c < 2; ++c) {
        #pragma unroll
        for (int nt = 0; nt < 4; ++nt) {
          int kcol = nt * 16 + (l & 15);
          int g = (c << 2) | (l >> 4);
          int off = kcol * 64 + ((g ^ (kcol & 7)) << 3);
          hfx8 kbh = *(hfx8*)&Ksh[off];
          hfx8 kbl = *(hfx8*)&Ksl[off];
          sacc[nt] = __builtin_amdgcn_mfma_f32_16x16x32_f16(qfh[c], kbh, sacc[nt], 0, 0, 0);
          sacc[nt] = __builtin_amdgcn_mfma_f32_16x16x32_f16(qfl[c], kbh, sacc[nt], 0, 0, 0);
          sacc[nt] = __builtin_amdgcn_mfma_f32_16x16x32_f16(qfh[c], kbl, sacc[nt], 0, 0, 0);
        }
      }
      if (kt == qi) {
        #pragma unroll
        for (int nt = 0; nt < 4; ++nt)
          #pragma unroll
          for (int r = 0; r < 4; ++r)
            if (nt * 16 + (l & 15) > w16 + ((l >> 4) << 2) + r) sacc[nt][r] = -3e38f;
      }
      // online softmax + P hi/lo to LDS (own wave's strip)
      float facr[4];
      #pragma unroll
      for (int r = 0; r < 4; ++r) {
        float mx = fmaxf(fmaxf(sacc[0][r], sacc[1][r]), fmaxf(sacc[2][r], sacc[3][r]));
        mx = fmaxf(mx, __shfl_xor(mx, 1));
        mx = fmaxf(mx, __shfl_xor(mx, 2));
        mx = fmaxf(mx, __shfl_xor(mx, 4));
        mx = fmaxf(mx, __shfl_xor(mx, 8));
        float mn = fmaxf(m[r], mx);
        float fac = __expf(SC * (m[r] - mn));
        m[r] = mn; facr[r] = fac;
        int prow = w16 + ((l >> 4) << 2) + r;
        int rk = (prow & 7);
        float ps = 0.f;
        #pragma unroll
        for (int nt = 0; nt < 4; ++nt) {
          float pv = __expf(SC * (sacc[nt][r] - mn));
          ps += pv;
          ushort ph = f2h(pv);
          ushort pl = f2h(pv - h2f(ph));
          int col = nt * 16 + (l & 15);
          int wa = prow * 64 + (((col >> 3) ^ rk) << 3) + (col & 7);
          Psh[grp][wa] = ph; Psl[grp][wa] = pl;
        }
        ps += __shfl_xor(ps, 1);
        ps += __shfl_xor(ps, 2);
        ps += __shfl_xor(ps, 4);
        ps += __shfl_xor(ps, 8);
        lsum[r] = lsum[r] * fac + ps;
      }
      #pragma unroll
      for (int nt = 0; nt < 4; ++nt)
        #pragma unroll
        for (int r = 0; r < 4; ++r) oacc[nt][r] *= facr[r];
      // PV: O[16 q][64 d] += P @ V   (P written by this wave; lgkmcnt orders)
      #pragma unroll
      for (int c = 0; c < 2; ++c) {
        int prow = w16 + (l & 15);
        int g = (c << 2) | (l >> 4);
        int offp = prow * 64 + ((g ^ (prow & 7)) << 3);
        hfx8 pah = *(hfx8*)&Psh[grp][offp];
        hfx8 pal = *(hfx8*)&Psl[grp][offp];
        #pragma unroll
        for (int nt = 0; nt < 4; ++nt) {
          int d = nt * 16 + (l & 15);
          int offv = d * 64 + ((g ^ (d & 7)) << 3);
          hfx8 vbh = *(hfx8*)&Vsh[offv];
          hfx8 vbl = *(hfx8*)&Vsl[offv];
          oacc[nt] = __builtin_amdgcn_mfma_f32_16x16x32_f16(pah, vbh, oacc[nt], 0, 0, 0);
          oacc[nt] = __builtin_amdgcn_mfma_f32_16x16x32_f16(pal, vbh, oacc[nt], 0, 0, 0);
          oacc[nt] = __builtin_amdgcn_mfma_f32_16x16x32_f16(pah, vbl, oacc[nt], 0, 0, 0);
        }
      }
    }
  }
  // epilogue: out = oacc/lsum (x64-scaled true value), hi/lo fp16
  #pragma unroll
  for (int r = 0; r < 4; ++r) {
    float inv = 1.0f / lsum[r];
    int s = qi * 64 + w16 + ((l >> 4) << 2) + r;
    #pragma unroll
    for (int nt = 0; nt < 4; ++nt) {
      int d = nt * 16 + (l & 15);
      float ot = oacc[nt][r] * inv;
      ushort hh = f2h(ot);
      ushort ll = f2h(ot - h2f(hh));
      size_t idx = ((size_t)b * 2048 + s) * 1024 + h * 64 + d;
      aoh[idx] = hh; aol[idx] = ll;
    }
  }
}

// ---------------- transpose + cast fp32 -> bf16 (z: 0-7 = W1, 8-15 = W2) ----------------
__global__ __launch_bounds__(256) void k_tcast(
    const float* __restrict__ inA, const float* __restrict__ inB,
    ushort* __restrict__ out, int R, int C) {
  __shared__ float tile[32][33];
  int z = blockIdx.z;
  const float* in = (z < 8) ? (inA + (size_t)z * R * C) : (inB + (size_t)(z - 8) * R * C);
  size_t zoff = (size_t)z * R * C;
  int bx = blockIdx.x * 32, by = blockIdx.y * 32;
  int tx = threadIdx.x & 31, ty = threadIdx.x >> 5;
  #pragma unroll
  for (int i = 0; i < 32; i += 8)
    tile[ty + i][tx] = in[(size_t)(by + ty + i) * C + bx + tx];
  __syncthreads();
  #pragma unroll
  for (int i = 0; i < 32; i += 8)
    out[zoff + (size_t)(bx + ty + i) * R + by + tx] = f2bf(tile[tx][ty + i]);
}

// ---------------- gating: one wave per token ----------------
__global__ __launch_bounds__(256) void k_gate(
    const float* __restrict__ post, const float* __restrict__ gw,
    float* __restrict__ w12, float* __restrict__ probs, int* __restrict__ sel) {
  int t = blockIdx.x * 4 + (threadIdx.x >> 6);
  int lane = threadIdx.x & 63;
  float acc[8] = {};
  const float* xr = post + (size_t)t * DD;
  for (int it = 0; it < 16; ++it) {
    int d = it * 64 + lane;
    float xd = xr[d];
    v4f g0 = *(const v4f*)(gw + d * 8);
    v4f g1 = *(const v4f*)(gw + d * 8 + 4);
    acc[0] = fmaf(xd, g0[0], acc[0]); acc[1] = fmaf(xd, g0[1], acc[1]);
    acc[2] = fmaf(xd, g0[2], acc[2]); acc[3] = fmaf(xd, g0[3], acc[3]);
    acc[4] = fmaf(xd, g1[0], acc[4]); acc[5] = fmaf(xd, g1[1], acc[5]);
    acc[6] = fmaf(xd, g1[2], acc[6]); acc[7] = fmaf(xd, g1[3], acc[7]);
  }
  #pragma unroll
  for (int e = 0; e < 8; ++e) {
    float s = acc[e];
    #pragma unroll
    for (int o = 32; o; o >>= 1) s += __shfl_down(s, o);
    acc[e] = s;
  }
  if (lane == 0) {
    float mx = acc[0];
    #pragma unroll
    for (int e = 1; e < 8; ++e) mx = fmaxf(mx, acc[e]);
    float p[8], sum = 0.f;
    #pragma unroll
    for (int e = 0; e < 8; ++e) { p[e] = __expf(acc[e] - mx); sum += p[e]; }
    float inv = 1.f / sum;
    #pragma unroll
    for (int e = 0; e < 8; ++e) p[e] *= inv;
    int e1 = 0; float l1 = acc[0];
    for (int e = 1; e < 8; ++e) if (acc[e] > l1) { l1 = acc[e]; e1 = e; }
    int e2 = -1; float l2 = -1e38f;
    for (int e = 0; e < 8; ++e) if (e != e1 && acc[e] > l2) { l2 = acc[e]; e2 = e; }
    float v1 = p[e1], v2 = p[e2];
    float s2 = 1.f / (v1 + v2);
    for (int e = 0; e < 8; ++e) probs[t * 8 + e] = p[e];
    w12[2 * t] = v1 * s2;
    w12[2 * t + 1] = v2 * s2;
    sel[t] = e1 * 8 + e2;
  }
}

// ---------------- routing: histogram + offsets (1 block) ----------------
__global__ __launch_bounds__(256) void k_count(
    const int* __restrict__ sel, int* __restrict__ offs) {
  __shared__ int h[8];
  int tid = threadIdx.x;
  if (tid < 8) h[tid] = 0;
  __syncthreads();
  for (int t = tid; t < NT; t += 256) {
    int s = sel[t];
    atomicAdd(&h[s >> 3], 1);
    atomicAdd(&h[s & 7], 1);
  }
  __syncthreads();
  if (tid == 0) {
    int run = 0;
    for (int e = 0; e < 8; ++e) { offs[e] = run; run += h[e]; }
    offs[8] = run;
  }
}

// ---------------- routing: stable placement (block e = expert e) ----------------
__global__ __launch_bounds__(256) void k_place(
    const int* __restrict__ sel, const int* __restrict__ offs,
    int* __restrict__ list, int* __restrict__ inv) {
  int e = blockIdx.x;
  int tid = threadIdx.x;
  __shared__ int a[256];
  int base = tid * 16;
  int c = 0;
  #pragma unroll
  for (int i = 0; i < 16; ++i) {
    int s = sel[base + i];
    c += ((s >> 3) == e) + ((s & 7) == e);
  }
  a[tid] = c;
  __syncthreads();
  for (int st = 1; st < 256; st <<= 1) {
    int tv = (tid >= st) ? a[tid - st] : 0;
    __syncthreads();
    a[tid] += tv;
    __syncthreads();
  }
  int slot = offs[e] + a[tid] - c;
  for (int i = 0; i < 16; ++i) {
    int t = base + i;
    int s = sel[t];
    if ((s >> 3) == e) { list[slot] = t; inv[2 * t] = slot; ++slot; }
    if ((s & 7) == e)  { list[slot] = t; inv[2 * t + 1] = slot; ++slot; }
  }
}

// ---------------- sparse expert GEMM: bf16 MFMA, 128x128 tile, z = expert ----------------
// Double-buffered direct global->LDS DMA, 2-phase pipeline.
template<int MODE>
__global__ __launch_bounds__(256) void k_moe_gemm(
    const ushort* __restrict__ A, const ushort* __restrict__ BtAll,
    ushort* __restrict__ hb, ushort* __restrict__ ob,
    const int* __restrict__ list, const int* __restrict__ offs,
    int N, int K) {
  int e = blockIdx.z;
  const ushort* Bt = BtAll + (size_t)e * DD * DD;
  int off = offs[e];
  int Me = offs[e + 1] - off;
  int m0 = blockIdx.x * 128;
  if (m0 >= Me) return;
  __shared__ ushort lA[2][128 * 32];
  __shared__ ushort lB[2][128 * 32];
  int tid = threadIdx.x;
  int l = tid & 63, wid = tid >> 6;
  int wm = wid >> 1, wn = wid & 1;
  int n0 = blockIdx.y * 128;
  fx4 zero = {0.f, 0.f, 0.f, 0.f};
  fx4 acc[4][4];
  #pragma unroll
  for (int mt = 0; mt < 4; ++mt)
    #pragma unroll
    for (int nt = 0; nt < 4; ++nt) acc[mt][nt] = zero;
  int sr = tid >> 2;
  int scg = (((l & 3) ^ ((l >> 2) & 3)) << 3);
  int dofs = wid * 512;
  int cr0 = m0 + sr;      if (cr0 > Me - 1) cr0 = Me - 1;
  int cr1 = m0 + sr + 64; if (cr1 > Me - 1) cr1 = Me - 1;
  size_t ar0, ar1;
  if (MODE == 0) { ar0 = (size_t)list[off + cr0]; ar1 = (size_t)list[off + cr1]; }
  else           { ar0 = (size_t)(off + cr0);     ar1 = (size_t)(off + cr1); }

#define ISSUE_MOE(BUF, KT)                                                       \
  do {                                                                           \
    GLOAD16(A  + ar0 * K + (KT) + scg,                    lA[BUF] + dofs);       \
    GLOAD16(A  + ar1 * K + (KT) + scg,                    lA[BUF] + 2048 + dofs);\
    GLOAD16(Bt + (size_t)(n0 + sr) * K + (KT) + scg,      lB[BUF] + dofs);       \
    GLOAD16(Bt + (size_t)(n0 + sr + 64) * K + (KT) + scg, lB[BUF] + 2048 + dofs);\
  } while (0)

#define COMP_MOE(BUF)                                                            \
  do {                                                                           \
    int kb = (l >> 4) << 4;                                                      \
    bfx8 bfr[4];                                                                 \
    _Pragma("unroll")                                                            \
    for (int nt = 0; nt < 4; ++nt) {                                             \
      int row = wn * 64 + nt * 16 + (l & 15);                                    \
      bfr[nt] = *(bfx8*)((char*)lB[BUF] + row * 64 + (kb ^ ((row & 3) << 4)));   \
    }                                                                            \
    _Pragma("unroll")                                                            \
    for (int mt = 0; mt < 4; ++mt) {                                             \
      int row = wm * 64 + mt * 16 + (l & 15);                                    \
      bfx8 af = *(bfx8*)((char*)lA[BUF] + row * 64 + (kb ^ ((row & 3) << 4)));   \
      _Pragma("unroll")                                                          \
      for (int nt = 0; nt < 4; ++nt)                                             \
        acc[mt][nt] = __builtin_amdgcn_mfma_f32_16x16x32_bf16(af, bfr[nt], acc[mt][nt], 0, 0, 0); \
    }                                                                            \
  } while (0)

  ISSUE_MOE(0, 0);
  for (int kt = 0; kt < K; kt += 64) {
    __syncthreads();
    if (kt + 32 < K) ISSUE_MOE(1, kt + 32);
    COMP_MOE(0);
    __syncthreads();
    if (kt + 64 < K) ISSUE_MOE(0, kt + 64);
    COMP_MOE(1);
  }
#undef ISSUE_MOE
#undef COMP_MOE

  #pragma unroll
  for (int mt = 0; mt < 4; ++mt)
    #pragma unroll
    for (int nt = 0; nt < 4; ++nt)
      #pragma unroll
      for (int r = 0; r < 4; ++r) {
        int rowt = wm * 64 + mt * 16 + ((l >> 4) << 2) + r;
        if (m0 + rowt < Me) {
          int col = n0 + wn * 64 + nt * 16 + (l & 15);
          float vv = acc[mt][nt][r];
          size_t idx = (size_t)(off + m0 + rowt) * N + col;
          if (MODE == 0) hb[idx] = f2bf(fmaxf(vv, 0.f));
          else           ob[idx] = f2bf(vv);
        }
      }
}

// ---------------- combine: out = psum + w1*o[inv1] + w2*o[inv2] (o in bf16) ----------------
__global__ __launch_bounds__(256) void k_combine(
    const float* __restrict__ psum, const ushort* __restrict__ ob,
    const int* __restrict__ inv, const float* __restrict__ w12,
    float* __restrict__ out) {
  int t = blockIdx.x;
  int d = threadIdx.x * 4;
  v4f a = *(const v4f*)(psum + (size_t)t * DD + d);
  ushort4 u1 = *(const ushort4*)(ob + (size_t)inv[2 * t] * DD + d);
  ushort4 u2 = *(const ushort4*)(ob + (size_t)inv[2 * t + 1] * DD + d);
  float w1 = w12[2 * t], w2 = w12[2 * t + 1];
  v4f r;
  r[0] = a[0] + w1 * b2f(u1.x) + w2 * b2f(u2.x);
  r[1] = a[1] + w1 * b2f(u1.y) + w2 * b2f(u2.y);
  r[2] = a[2] + w1 * b2f(u1.z) + w2 * b2f(u2.z);
  r[3] = a[3] + w1 * b2f(u1.w) + w2 * b2f(u2.w);
  *(v4f*)(out + (size_t)t * DD + d) = r;
}

// ---------------- aux loss: deterministic single-block reduce ----------------
__global__ __launch_bounds__(256) void k_aux(
    const float* __restrict__ probs, const int* __restrict__ sel,
    float* __restrict__ auxout) {
  int tid = threadIdx.x;
  float ps[8] = {}, cs[8] = {};
  for (int t = tid; t < NT; t += 256) {
    #pragma unroll
    for (int e = 0; e < 8; ++e) ps[e] += probs[t * 8 + e];
    int s = sel[t];
    cs[s >> 3] += 1.f; cs[s & 7] += 1.f;
  }
  __shared__ float red[4];
  __shared__ float tot[16];
  #pragma unroll
  for (int vv = 0; vv < 16; ++vv) {
    float s = (vv < 8) ? ps[vv] : cs[vv - 8];
    #pragma unroll
    for (int o = 32; o; o >>= 1) s += __shfl_down(s, o);
    __syncthreads();
    if ((tid & 63) == 0) red[tid >> 6] = s;
    __syncthreads();
    if (tid == 0) tot[vv] = red[0] + red[1] + red[2] + red[3];
  }
  __syncthreads();
  if (tid == 0) {
    float aux = 0.f;
    for (int e = 0; e < 8; ++e)
      aux += (tot[8 + e] * (1.f / NT)) * (tot[e] * (1.f / NT));
    auxout[0] = 8.f * aux;
  }
}

extern "C" void kernel_launch(void* const* d_in, const int* in_sizes, int n_in,
                              void* d_out, int out_size, void* d_ws, size_t ws_size,
                              hipStream_t stream) {
  (void)in_sizes; (void)n_in; (void)out_size; (void)ws_size;
  const float* x     = (const float*)d_in[0];
  const float* wpre  = (const float*)d_in[1];
  const float* wpost = (const float*)d_in[2];
  const float* Wq    = (const float*)d_in[3];
  const float* Wk    = (const float*)d_in[4];
  const float* Wv    = (const float*)d_in[5];
  const float* Wo    = (const float*)d_in[6];
  const float* gw    = (const float*)d_in[7];
  const float* W1    = (const float*)d_in[8];
  const float* W2    = (const float*)d_in[9];
  float* out = (float*)d_out;
  char* ws = (char*)d_ws;
  const size_t MB = 1ull << 20;
  // phase-overlaid workspace map (112MB + tail)
  ushort* preh  = (ushort*)(ws + 0 * MB);   // 8MB  -> aoh -> hb(16MB @0)
  ushort* prel  = (ushort*)(ws + 8 * MB);   // 8MB  -> aol
  ushort* qh    = (ushort*)(ws + 16 * MB);  // 8MB  -> postf (16MB @16)
  ushort* ql    = (ushort*)(ws + 24 * MB);  // 8MB
  ushort* kh    = (ushort*)(ws + 32 * MB);  // 8MB  -> postb (8MB @32)
  ushort* kl    = (ushort*)(ws + 40 * MB);  // 8MB  -> ob (16MB @40)
  ushort* vth   = (ushort*)(ws + 48 * MB);  // 8MB
  ushort* vtl   = (ushort*)(ws + 56 * MB);  // 8MB
  float*  psum  = (float*)(ws + 64 * MB);   // 16MB (live to end)
  ushort* Wt4h  = (ushort*)(ws + 80 * MB);  // 8MB  -> W1t (16MB @80)
  ushort* Wt4l  = (ushort*)(ws + 88 * MB);  // 8MB
  ushort* W2t   = (ushort*)(ws + 96 * MB);  // 16MB
  ushort* W1t   = (ushort*)(ws + 80 * MB);
  ushort* aoh   = preh;
  ushort* aol   = prel;
  float*  postf = (float*)(ws + 16 * MB);
  ushort* postb = (ushort*)(ws + 32 * MB);
  ushort* hb    = (ushort*)(ws + 0 * MB);
  ushort* ob    = (ushort*)(ws + 40 * MB);
  float*  probs = (float*)(ws + 112 * MB);
  int*    sel   = (int*)(ws + 112 * MB + (128u << 10));
  float*  w12   = (float*)(ws + 112 * MB + (160u << 10));
  int*    list  = (int*)(ws + 112 * MB + (192u << 10));
  int*    offs  = (int*)(ws + 112 * MB + (224u << 10));
  int*    inv   = (int*)(ws + 112 * MB + (256u << 10));

  // pre-norm -> fp16 hi/lo (x64)
  k_rmsnorm<<<NT, 256, 0, stream>>>(x, wpre, nullptr, nullptr, preh, prel);
  // weight transpose+split for Wq/Wk/Wv/Wo
  k_wsplit<<<dim3(32, 32, 4), 256, 0, stream>>>(Wq, Wk, Wv, Wo, Wt4h, Wt4l);
  // QKV via split-fp16 MFMA (128x128 tile, double-buffered DMA pipeline)
  k_gemm_sp<0><<<dim3(32, 8, 3), 256, 0, stream>>>(
      preh, prel, Wt4h, Wt4l, nullptr, nullptr, qh, ql, kh, kl, vth, vtl);
  // MFMA flash attention (R13 body + XCD-clustered flat grid) -> hi/lo fp16
  k_attn<<<512, 512, 0, stream>>>(qh, ql, kh, kl, vth, vtl, aoh, aol);
  // Wo + residual -> post_sum (split-fp16 MFMA, double-buffered DMA pipeline)
  k_gemm_sp<1><<<dim3(32, 8, 1), 256, 0, stream>>>(
      aoh, aol, Wt4h + (size_t)3 * DD * DD, Wt4l + (size_t)3 * DD * DD,
      psum, x, nullptr, nullptr, nullptr, nullptr, nullptr, nullptr);
  // post-norm: fp32 (gating) + bf16 (MoE A operand)
  k_rmsnorm<<<NT, 256, 0, stream>>>(psum, wpost, postf, postb, nullptr, nullptr);
  // expert weights -> bf16 transposed (both W1 and W2 in one dispatch)
  k_tcast<<<dim3(32, 32, 16), 256, 0, stream>>>(W1, W2, W1t, DD, DD);
  // gating (fp32, exact top-k path)
  k_gate<<<NT / 4, 256, 0, stream>>>(postf, gw, w12, probs, sel);
  // routing
  k_count<<<1, 256, 0, stream>>>(sel, offs);
  k_place<<<8, 256, 0, stream>>>(sel, offs, list, inv);
  // sparse MoE: all experts in one dispatch per stage (z = expert), 128x128 tiles
  k_moe_gemm<0><<<dim3(32, 8, 8), 256, 0, stream>>>(
      postb, W1t, hb, nullptr, list, offs, DD, DD);
  k_moe_gemm<1><<<dim3(32, 8, 8), 256, 0, stream>>>(
      hb, W2t, nullptr, ob, list, offs, DD, DD);
  // combine + aux
  k_combine<<<NT, 256, 0, stream>>>(psum, ob, inv, w12, out);
  k_aux<<<1, 256, 0, stream>>>(probs, sel, out + 4194304);
}

// Round 18
// 405.895 us; speedup vs baseline: 1.3251x; 1.2484x over previous
//
#include <hip/hip_runtime.h>
#include <hip/hip_bf16.h>

#define DD 1024
#define NHD 64
#define NHEAD 16
#define NE 8
#define NT 4096
#define SS 2048

typedef float v4f __attribute__((ext_vector_type(4)));
typedef short bfx8 __attribute__((ext_vector_type(8)));
typedef float fx4 __attribute__((ext_vector_type(4)));
typedef _Float16 hfx8 __attribute__((ext_vector_type(8)));
typedef unsigned int u32;

// direct global->LDS DMA, 16B per lane; LDS dest = uniform base + lane*16
#define GLOAD16(gp, lp)                                                     \
  __builtin_amdgcn_global_load_lds(                                         \
      (const __attribute__((address_space(1))) u32*)(const u32*)(gp),       \
      (__attribute__((address_space(3))) u32*)(u32*)(lp), 16, 0, 0)

__device__ inline ushort f2bf(float f) {
  union { float f; unsigned u; } x; x.f = f;
  unsigned r = (x.u + 0x7FFFu + ((x.u >> 16) & 1u)) >> 16;
  return (ushort)r;
}
__device__ inline float b2f(ushort u) {
  union { unsigned u; float f; } x; x.u = ((unsigned)u) << 16;
  return x.f;
}
__device__ inline ushort f2h(float f) {
  union { _Float16 h; ushort u; } c; c.h = (_Float16)f; return c.u;
}
__device__ inline float h2f(ushort u) {
  union { ushort u; _Float16 h; } c; c.u = u; return (float)c.h;
}

// ---------------- RMSNorm: one block per row ----------------
__global__ __launch_bounds__(256) void k_rmsnorm(
    const float* __restrict__ x, const float* __restrict__ w,
    float* __restrict__ of32, ushort* __restrict__ obf,
    ushort* __restrict__ oh, ushort* __restrict__ ol) {
  int row = blockIdx.x;
  int tid = threadIdx.x;
  v4f v = *(const v4f*)(x + (size_t)row * DD + tid * 4);
  float ss = v[0]*v[0] + v[1]*v[1] + v[2]*v[2] + v[3]*v[3];
  #pragma unroll
  for (int o = 32; o; o >>= 1) ss += __shfl_down(ss, o);
  __shared__ float red[4];
  if ((tid & 63) == 0) red[tid >> 6] = ss;
  __syncthreads();
  float tot = red[0] + red[1] + red[2] + red[3];
  float sc = rsqrtf(tot * (1.0f / DD) + 1e-5f);
  v4f wv = *(const v4f*)(w + tid * 4);
  v4f o;
  o[0] = v[0]*sc*wv[0]; o[1] = v[1]*sc*wv[1];
  o[2] = v[2]*sc*wv[2]; o[3] = v[3]*sc*wv[3];
  if (of32) *(v4f*)(of32 + (size_t)row * DD + tid * 4) = o;
  if (obf) {
    ushort4 ub;
    ub.x = f2bf(o[0]); ub.y = f2bf(o[1]); ub.z = f2bf(o[2]); ub.w = f2bf(o[3]);
    *(ushort4*)(obf + (size_t)row * DD + tid * 4) = ub;
  }
  if (oh) {
    ushort4 uh, ul;
    float s0 = o[0]*64.f, s1 = o[1]*64.f, s2 = o[2]*64.f, s3 = o[3]*64.f;
    uh.x = f2h(s0); uh.y = f2h(s1); uh.z = f2h(s2); uh.w = f2h(s3);
    ul.x = f2h(s0 - h2f(uh.x)); ul.y = f2h(s1 - h2f(uh.y));
    ul.z = f2h(s2 - h2f(uh.z)); ul.w = f2h(s3 - h2f(uh.w));
    *(ushort4*)(oh + (size_t)row * DD + tid * 4) = uh;
    *(ushort4*)(ol + (size_t)row * DD + tid * 4) = ul;
  }
}

// ---------------- weight transpose + fp16 split (x64): Wt[z][n][k] ----------------
__global__ __launch_bounds__(256) void k_wsplit(
    const float* __restrict__ Wq, const float* __restrict__ Wk,
    const float* __restrict__ Wv, const float* __restrict__ Wo,
    ushort* __restrict__ oh, ushort* __restrict__ ol) {
  __shared__ float tile[32][33];
  int z = blockIdx.z;
  const float* in = (z == 0) ? Wq : (z == 1) ? Wk : (z == 2) ? Wv : Wo;
  size_t zoff = (size_t)z * DD * DD;
  int bx = blockIdx.x * 32, by = blockIdx.y * 32;
  int tx = threadIdx.x & 31, ty = threadIdx.x >> 5;
  #pragma unroll
  for (int i = 0; i < 32; i += 8)
    tile[ty + i][tx] = in[(size_t)(by + ty + i) * DD + bx + tx];
  __syncthreads();
  #pragma unroll
  for (int i = 0; i < 32; i += 8) {
    float vv = tile[tx][ty + i] * 64.f;
    ushort hh = f2h(vv);
    size_t idx = zoff + (size_t)(bx + ty + i) * DD + by + tx;
    oh[idx] = hh;
    ol[idx] = f2h(vv - h2f(hh));
  }
}

// ---------------- split-fp16 MFMA GEMM, 128x128 tile, BK=32, 4 waves ----------------
// Double-buffered direct global->LDS DMA, 2-phase pipeline.
// Flat grid, XCD-chunked: wid = (f&7)*(total/8) + (f>>3); n-tile fastest.
// MODE 0 (QKV): 768 blocks, z = wid>>8 selects B slab.  MODE 1 (Wo): 256 blocks.
template<int MODE>
__global__ __launch_bounds__(256) void k_gemm_sp(
    const ushort* __restrict__ Ah, const ushort* __restrict__ Al,
    const ushort* __restrict__ Bth, const ushort* __restrict__ Btl,
    float* __restrict__ C0, const float* __restrict__ resid,
    ushort* __restrict__ o0h, ushort* __restrict__ o0l,
    ushort* __restrict__ o1h, ushort* __restrict__ o1l,
    ushort* __restrict__ o2h, ushort* __restrict__ o2l) {
  const int N = DD, K = DD;
  int f = blockIdx.x;
  int wid2 = (MODE == 0) ? ((f & 7) * 96 + (f >> 3)) : ((f & 7) * 32 + (f >> 3));
  int z = (MODE == 0) ? (wid2 >> 8) : 0;
  int rem = wid2 & 255;
  int n0 = (rem & 7) * 128;
  int m0 = (rem >> 3) * 128;
  if (MODE == 0) {
    Bth += (size_t)z * DD * DD; Btl += (size_t)z * DD * DD;
  }
  __shared__ ushort lAh[2][128 * 32];
  __shared__ ushort lAl[2][128 * 32];
  __shared__ ushort lBh[2][128 * 32];
  __shared__ ushort lBl[2][128 * 32];
  int tid = threadIdx.x;
  int l = tid & 63, wid = tid >> 6;
  int wm = wid >> 1, wn = wid & 1;
  fx4 zero = {0.f, 0.f, 0.f, 0.f};
  fx4 acc[4][4];
  #pragma unroll
  for (int mt = 0; mt < 4; ++mt)
    #pragma unroll
    for (int nt = 0; nt < 4; ++nt) acc[mt][nt] = zero;
  int sr = tid >> 2;
  int scg = (((l & 3) ^ ((l >> 2) & 3)) << 3);
  int dofs = wid * 512;

#define ISSUE_SP(BUF, KT)                                                        \
  do {                                                                           \
    GLOAD16(Ah  + (size_t)(m0 + sr) * K + (KT) + scg,      lAh[BUF] + dofs);     \
    GLOAD16(Ah  + (size_t)(m0 + sr + 64) * K + (KT) + scg, lAh[BUF] + 2048 + dofs); \
    GLOAD16(Al  + (size_t)(m0 + sr) * K + (KT) + scg,      lAl[BUF] + dofs);     \
    GLOAD16(Al  + (size_t)(m0 + sr + 64) * K + (KT) + scg, lAl[BUF] + 2048 + dofs); \
    GLOAD16(Bth + (size_t)(n0 + sr) * K + (KT) + scg,      lBh[BUF] + dofs);     \
    GLOAD16(Bth + (size_t)(n0 + sr + 64) * K + (KT) + scg, lBh[BUF] + 2048 + dofs); \
    GLOAD16(Btl + (size_t)(n0 + sr) * K + (KT) + scg,      lBl[BUF] + dofs);     \
    GLOAD16(Btl + (size_t)(n0 + sr + 64) * K + (KT) + scg, lBl[BUF] + 2048 + dofs); \
  } while (0)

#define COMP_SP(BUF)                                                             \
  do {                                                                           \
    int kb = (l >> 4) << 4;                                                      \
    hfx8 bfh[4], bfl[4];                                                         \
    _Pragma("unroll")                                                            \
    for (int nt = 0; nt < 4; ++nt) {                                             \
      int row = wn * 64 + nt * 16 + (l & 15);                                    \
      int off = row * 64 + (kb ^ ((row & 3) << 4));                              \
      bfh[nt] = *(hfx8*)((char*)lBh[BUF] + off);                                 \
      bfl[nt] = *(hfx8*)((char*)lBl[BUF] + off);                                 \
    }                                                                            \
    _Pragma("unroll")                                                            \
    for (int mt = 0; mt < 4; ++mt) {                                             \
      int row = wm * 64 + mt * 16 + (l & 15);                                    \
      int off = row * 64 + (kb ^ ((row & 3) << 4));                              \
      hfx8 afh = *(hfx8*)((char*)lAh[BUF] + off);                                \
      hfx8 afl = *(hfx8*)((char*)lAl[BUF] + off);                                \
      _Pragma("unroll")                                                          \
      for (int nt = 0; nt < 4; ++nt) {                                           \
        acc[mt][nt] = __builtin_amdgcn_mfma_f32_16x16x32_f16(afh, bfh[nt], acc[mt][nt], 0, 0, 0); \
        acc[mt][nt] = __builtin_amdgcn_mfma_f32_16x16x32_f16(afl, bfh[nt], acc[mt][nt], 0, 0, 0); \
        acc[mt][nt] = __builtin_amdgcn_mfma_f32_16x16x32_f16(afh, bfl[nt], acc[mt][nt], 0, 0, 0); \
      }                                                                          \
    }                                                                            \
  } while (0)

  ISSUE_SP(0, 0);
  for (int kt = 0; kt < K; kt += 64) {
    __syncthreads();
    if (kt + 32 < K) ISSUE_SP(1, kt + 32);
    COMP_SP(0);
    __syncthreads();
    if (kt + 64 < K) ISSUE_SP(0, kt + 64);
    COMP_SP(1);
  }
#undef ISSUE_SP
#undef COMP_SP

  if (MODE == 1) {
    const float SCI = 1.0f / 4096.0f;
    #pragma unroll
    for (int mt = 0; mt < 4; ++mt)
      #pragma unroll
      for (int nt = 0; nt < 4; ++nt)
        #pragma unroll
        for (int r = 0; r < 4; ++r) {
          int row = m0 + wm * 64 + mt * 16 + ((l >> 4) << 2) + r;
          int col = n0 + wn * 64 + nt * 16 + (l & 15);
          size_t idx = (size_t)row * N + col;
          C0[idx] = acc[mt][nt][r] * SCI + resid[idx];
        }
  } else {
    const float SCO = 1.0f / 64.0f;
    ushort* oh = (z == 0) ? o0h : (z == 1) ? o1h : o2h;
    ushort* ol = (z == 0) ? o0l : (z == 1) ? o1l : o2l;
    #pragma unroll
    for (int mt = 0; mt < 4; ++mt)
      #pragma unroll
      for (int nt = 0; nt < 4; ++nt) {
        if (z < 2) {
          #pragma unroll
          for (int r = 0; r < 4; ++r) {
            int t = m0 + wm * 64 + mt * 16 + ((l >> 4) << 2) + r;
            int c = n0 + wn * 64 + nt * 16 + (l & 15);
            float vv = acc[mt][nt][r] * SCO;
            ushort hh = f2h(vv);
            ushort ll = f2h(vv - h2f(hh));
            size_t idx = (size_t)(((t >> 11) << 4) + (c >> 6)) * 131072 +
                         (size_t)(t & 2047) * 64 + (c & 63);
            oh[idx] = hh; ol[idx] = ll;
          }
        } else {
          int t0 = m0 + wm * 64 + mt * 16 + ((l >> 4) << 2);
          int c = n0 + wn * 64 + nt * 16 + (l & 15);
          ushort4 uh, ul;
          float v0 = acc[mt][nt][0] * SCO, v1 = acc[mt][nt][1] * SCO;
          float v2 = acc[mt][nt][2] * SCO, v3 = acc[mt][nt][3] * SCO;
          uh.x = f2h(v0); uh.y = f2h(v1); uh.z = f2h(v2); uh.w = f2h(v3);
          ul.x = f2h(v0 - h2f(uh.x)); ul.y = f2h(v1 - h2f(uh.y));
          ul.z = f2h(v2 - h2f(uh.z)); ul.w = f2h(v3 - h2f(uh.w));
          size_t idx = (size_t)(((t0 >> 11) << 4) + (c >> 6)) * 131072 +
                       (size_t)(c & 63) * 2048 + (t0 & 2047);
          *(ushort4*)(oh + idx) = uh;
          *(ushort4*)(ol + idx) = ul;
        }
      }
  }
}

// ---------------- MFMA flash attention (causal), split-fp16 ----------------
// R17-proven: pair config + DMA staging + XCD-clustered flat grid.
__global__ __launch_bounds__(512, 4) void k_attn(
    const ushort* __restrict__ qh, const ushort* __restrict__ ql,
    const ushort* __restrict__ kh, const ushort* __restrict__ kl,
    const ushort* __restrict__ vth, const ushort* __restrict__ vtl,
    ushort* __restrict__ aoh, ushort* __restrict__ aol) {
  __shared__ ushort Ksh[64 * 64];
  __shared__ ushort Ksl[64 * 64];
  __shared__ ushort Vsh[64 * 64];
  __shared__ ushort Vsl[64 * 64];
  __shared__ ushort Psh[2][64 * 64];
  __shared__ ushort Psl[2][64 * 64];
  const float SC = 0.125f / 4096.0f;
  int f = blockIdx.x;                  // 0..511, XCD-clustered mapping
  int idx8 = f >> 3;                   // 0..63
  int bhv = ((f & 7) << 2) | (idx8 >> 4);   // 4 bh per XCD
  int p = idx8 & 15;                   // 0..15
  int b = bhv >> 4, h = bhv & 15;
  int tid = threadIdx.x;
  int l = tid & 63, wid = tid >> 6;   // 8 waves
  int grp = wid >> 2;                  // 0: qi=31-p, 1: qi=p
  int w16 = (wid & 3) * 16;
  int qi = grp ? p : (31 - p);
  int qiMax = 31 - p;
  // staging: buffer = tid>>7 (Kh,Kl,Vh,Vl); 2 waves per buffer
  int bsel = tid >> 7;
  int wh = (tid >> 6) & 1;    // which half of rows (0..31 / 32..63)
  int sr8 = l >> 3;           // row mod 8
  int gsw = (l & 7) ^ sr8;    // pre-swizzled source granule (LDS dest is lane-linear)
  size_t base_k = (size_t)bhv * 131072;
  const ushort* gsrc0;
  int rstr, kstep;
  ushort* lbuf;
  if (bsel == 0)      { gsrc0 = kh  + base_k; rstr = 64;   kstep = 4096; lbuf = Ksh; }
  else if (bsel == 1) { gsrc0 = kl  + base_k; rstr = 64;   kstep = 4096; lbuf = Ksl; }
  else if (bsel == 2) { gsrc0 = vth + base_k; rstr = 2048; kstep = 64;   lbuf = Vsh; }
  else                { gsrc0 = vtl + base_k; rstr = 2048; kstep = 64;   lbuf = Vsl; }
  // Q fragments in registers
  hfx8 qfh[2], qfl[2];
  {
    int qrow = qi * 64 + w16 + (l & 15);
    size_t qo = base_k + (size_t)qrow * 64 + ((l >> 4) << 3);
    qfh[0] = *(const hfx8*)(qh + qo);
    qfh[1] = *(const hfx8*)(qh + qo + 32);
    qfl[0] = *(const hfx8*)(ql + qo);
    qfl[1] = *(const hfx8*)(ql + qo + 32);
  }
  float m[4], lsum[4];
  fx4 oacc[4];
  #pragma unroll
  for (int r = 0; r < 4; ++r) { m[r] = -3e38f; lsum[r] = 0.f; }
  #pragma unroll
  for (int nt = 0; nt < 4; ++nt) oacc[nt] = fx4{0.f, 0.f, 0.f, 0.f};
  for (int kt = 0; kt <= qiMax; ++kt) {
    __syncthreads();   // (A) prev-iter LDS readers done; LDS free
    {
      const ushort* gs = gsrc0 + (size_t)kt * kstep;
      #pragma unroll
      for (int i = 0; i < 4; ++i)
        GLOAD16(gs + (size_t)(wh * 32 + i * 8 + sr8) * rstr + (gsw << 3),
                lbuf + (wh * 32 + i * 8) * 64);
    }
    __syncthreads();   // (B) DMA drained; tiles visible
    if (kt <= qi) {
      // QK^T: S[16 q][64 k]
      fx4 sacc[4];
      #pragma unroll
      for (int nt = 0; nt < 4; ++nt) sacc[nt] = fx4{0.f, 0.f, 0.f, 0.f};
      #pragma unroll
      for (int c = 0; c < 2; ++c) {
        #pragma unroll
        for (int nt = 0; nt < 4; ++nt) {
          int kcol = nt * 16 + (l & 15);
          int g = (c << 2) | (l >> 4);
          int off = kcol * 64 + ((g ^ (kcol & 7)) << 3);
          hfx8 kbh = *(hfx8*)&Ksh[off];
          hfx8 kbl = *(hfx8*)&Ksl[off];
          sacc[nt] = __builtin_amdgcn_mfma_f32_16x16x32_f16(qfh[c], kbh, sacc[nt], 0, 0, 0);
          sacc[nt] = __builtin_amdgcn_mfma_f32_16x16x32_f16(qfl[c], kbh, sacc[nt], 0, 0, 0);
          sacc[nt] = __builtin_amdgcn_mfma_f32_16x16x32_f16(qfh[c], kbl, sacc[nt], 0, 0, 0);
        }
      }
      if (kt == qi) {
        #pragma unroll
        for (int nt = 0; nt < 4; ++nt)
          #pragma unroll
          for (int r = 0; r < 4; ++r)
            if (nt * 16 + (l & 15) > w16 + ((l >> 4) << 2) + r) sacc[nt][r] = -3e38f;
      }
      // online softmax + P hi/lo to LDS (own wave's strip)
      float facr[4];
      #pragma unroll
      for (int r = 0; r < 4; ++r) {
        float mx = fmaxf(fmaxf(sacc[0][r], sacc[1][r]), fmaxf(sacc[2][r], sacc[3][r]));
        mx = fmaxf(mx, __shfl_xor(mx, 1));
        mx = fmaxf(mx, __shfl_xor(mx, 2));
        mx = fmaxf(mx, __shfl_xor(mx, 4));
        mx = fmaxf(mx, __shfl_xor(mx, 8));
        float mn = fmaxf(m[r], mx);
        float fac = __expf(SC * (m[r] - mn));
        m[r] = mn; facr[r] = fac;
        int prow = w16 + ((l >> 4) << 2) + r;
        int rk = (prow & 7);
        float ps = 0.f;
        #pragma unroll
        for (int nt = 0; nt < 4; ++nt) {
          float pv = __expf(SC * (sacc[nt][r] - mn));
          ps += pv;
          ushort ph = f2h(pv);
          ushort pl = f2h(pv - h2f(ph));
          int col = nt * 16 + (l & 15);
          int wa = prow * 64 + (((col >> 3) ^ rk) << 3) + (col & 7);
          Psh[grp][wa] = ph; Psl[grp][wa] = pl;
        }
        ps += __shfl_xor(ps, 1);
        ps += __shfl_xor(ps, 2);
        ps += __shfl_xor(ps, 4);
        ps += __shfl_xor(ps, 8);
        lsum[r] = lsum[r] * fac + ps;
      }
      #pragma unroll
      for (int nt = 0; nt < 4; ++nt)
        #pragma unroll
        for (int r = 0; r < 4; ++r) oacc[nt][r] *= facr[r];
      // PV: O[16 q][64 d] += P @ V   (P written by this wave; lgkmcnt orders)
      #pragma unroll
      for (int c = 0; c < 2; ++c) {
        int prow = w16 + (l & 15);
        int g = (c << 2) | (l >> 4);
        int offp = prow * 64 + ((g ^ (prow & 7)) << 3);
        hfx8 pah = *(hfx8*)&Psh[grp][offp];
        hfx8 pal = *(hfx8*)&Psl[grp][offp];
        #pragma unroll
        for (int nt = 0; nt < 4; ++nt) {
          int d = nt * 16 + (l & 15);
          int offv = d * 64 + ((g ^ (d & 7)) << 3);
          hfx8 vbh = *(hfx8*)&Vsh[offv];
          hfx8 vbl = *(hfx8*)&Vsl[offv];
          oacc[nt] = __builtin_amdgcn_mfma_f32_16x16x32_f16(pah, vbh, oacc[nt], 0, 0, 0);
          oacc[nt] = __builtin_amdgcn_mfma_f32_16x16x32_f16(pal, vbh, oacc[nt], 0, 0, 0);
          oacc[nt] = __builtin_amdgcn_mfma_f32_16x16x32_f16(pah, vbl, oacc[nt], 0, 0, 0);
        }
      }
    }
  }
  // epilogue: out = oacc/lsum (x64-scaled true value), hi/lo fp16
  #pragma unroll
  for (int r = 0; r < 4; ++r) {
    float inv = 1.0f / lsum[r];
    int s = qi * 64 + w16 + ((l >> 4) << 2) + r;
    #pragma unroll
    for (int nt = 0; nt < 4; ++nt) {
      int d = nt * 16 + (l & 15);
      float ot = oacc[nt][r] * inv;
      ushort hh = f2h(ot);
      ushort ll = f2h(ot - h2f(hh));
      size_t idx = ((size_t)b * 2048 + s) * 1024 + h * 64 + d;
      aoh[idx] = hh; aol[idx] = ll;
    }
  }
}

// ---------------- transpose + cast fp32 -> bf16 (z: 0-7 = W1, 8-15 = W2) ----------------
__global__ __launch_bounds__(256) void k_tcast(
    const float* __restrict__ inA, const float* __restrict__ inB,
    ushort* __restrict__ out, int R, int C) {
  __shared__ float tile[32][33];
  int z = blockIdx.z;
  const float* in = (z < 8) ? (inA + (size_t)z * R * C) : (inB + (size_t)(z - 8) * R * C);
  size_t zoff = (size_t)z * R * C;
  int bx = blockIdx.x * 32, by = blockIdx.y * 32;
  int tx = threadIdx.x & 31, ty = threadIdx.x >> 5;
  #pragma unroll
  for (int i = 0; i < 32; i += 8)
    tile[ty + i][tx] = in[(size_t)(by + ty + i) * C + bx + tx];
  __syncthreads();
  #pragma unroll
  for (int i = 0; i < 32; i += 8)
    out[zoff + (size_t)(bx + ty + i) * R + by + tx] = f2bf(tile[tx][ty + i]);
}

// ---------------- gating: one wave per token ----------------
__global__ __launch_bounds__(256) void k_gate(
    const float* __restrict__ post, const float* __restrict__ gw,
    float* __restrict__ w12, float* __restrict__ probs, int* __restrict__ sel) {
  int t = blockIdx.x * 4 + (threadIdx.x >> 6);
  int lane = threadIdx.x & 63;
  float acc[8] = {};
  const float* xr = post + (size_t)t * DD;
  for (int it = 0; it < 16; ++it) {
    int d = it * 64 + lane;
    float xd = xr[d];
    v4f g0 = *(const v4f*)(gw + d * 8);
    v4f g1 = *(const v4f*)(gw + d * 8 + 4);
    acc[0] = fmaf(xd, g0[0], acc[0]); acc[1] = fmaf(xd, g0[1], acc[1]);
    acc[2] = fmaf(xd, g0[2], acc[2]); acc[3] = fmaf(xd, g0[3], acc[3]);
    acc[4] = fmaf(xd, g1[0], acc[4]); acc[5] = fmaf(xd, g1[1], acc[5]);
    acc[6] = fmaf(xd, g1[2], acc[6]); acc[7] = fmaf(xd, g1[3], acc[7]);
  }
  #pragma unroll
  for (int e = 0; e < 8; ++e) {
    float s = acc[e];
    #pragma unroll
    for (int o = 32; o; o >>= 1) s += __shfl_down(s, o);
    acc[e] = s;
  }
  if (lane == 0) {
    float mx = acc[0];
    #pragma unroll
    for (int e = 1; e < 8; ++e) mx = fmaxf(mx, acc[e]);
    float p[8], sum = 0.f;
    #pragma unroll
    for (int e = 0; e < 8; ++e) { p[e] = __expf(acc[e] - mx); sum += p[e]; }
    float inv = 1.f / sum;
    #pragma unroll
    for (int e = 0; e < 8; ++e) p[e] *= inv;
    int e1 = 0; float l1 = acc[0];
    for (int e = 1; e < 8; ++e) if (acc[e] > l1) { l1 = acc[e]; e1 = e; }
    int e2 = -1; float l2 = -1e38f;
    for (int e = 0; e < 8; ++e) if (e != e1 && acc[e] > l2) { l2 = acc[e]; e2 = e; }
    float v1 = p[e1], v2 = p[e2];
    float s2 = 1.f / (v1 + v2);
    for (int e = 0; e < 8; ++e) probs[t * 8 + e] = p[e];
    w12[2 * t] = v1 * s2;
    w12[2 * t + 1] = v2 * s2;
    sel[t] = e1 * 8 + e2;
  }
}

// ---------------- routing: histogram + offsets (1 block) ----------------
__global__ __launch_bounds__(256) void k_count(
    const int* __restrict__ sel, int* __restrict__ offs) {
  __shared__ int h[8];
  int tid = threadIdx.x;
  if (tid < 8) h[tid] = 0;
  __syncthreads();
  for (int t = tid; t < NT; t += 256) {
    int s = sel[t];
    atomicAdd(&h[s >> 3], 1);
    atomicAdd(&h[s & 7], 1);
  }
  __syncthreads();
  if (tid == 0) {
    int run = 0;
    for (int e = 0; e < 8; ++e) { offs[e] = run; run += h[e]; }
    offs[8] = run;
  }
}

// ---------------- routing: stable placement (block e = expert e) ----------------
__global__ __launch_bounds__(256) void k_place(
    const int* __restrict__ sel, const int* __restrict__ offs,
    int* __restrict__ list, int* __restrict__ inv) {
  int e = blockIdx.x;
  int tid = threadIdx.x;
  __shared__ int a[256];
  int base = tid * 16;
  int c = 0;
  #pragma unroll
  for (int i = 0; i < 16; ++i) {
    int s = sel[base + i];
    c += ((s >> 3) == e) + ((s & 7) == e);
  }
  a[tid] = c;
  __syncthreads();
  for (int st = 1; st < 256; st <<= 1) {
    int tv = (tid >= st) ? a[tid - st] : 0;
    __syncthreads();
    a[tid] += tv;
    __syncthreads();
  }
  int slot = offs[e] + a[tid] - c;
  for (int i = 0; i < 16; ++i) {
    int t = base + i;
    int s = sel[t];
    if ((s >> 3) == e) { list[slot] = t; inv[2 * t] = slot; ++slot; }
    if ((s & 7) == e)  { list[slot] = t; inv[2 * t + 1] = slot; ++slot; }
  }
}

// ---------------- sparse expert GEMM: bf16 MFMA, 128x128 tile ----------------
// Flat 2048-block grid, XCD-chunked: each XCD hosts exactly one expert slab.
template<int MODE>
__global__ __launch_bounds__(256) void k_moe_gemm(
    const ushort* __restrict__ A, const ushort* __restrict__ BtAll,
    ushort* __restrict__ hb, ushort* __restrict__ ob,
    const int* __restrict__ list, const int* __restrict__ offs,
    int N, int K) {
  int f = blockIdx.x;
  int wid2 = (f & 7) * 256 + (f >> 3);
  int e = wid2 >> 8;
  int rem = wid2 & 255;
  int n0 = (rem & 7) * 128;
  int m0 = (rem >> 3) * 128;
  const ushort* Bt = BtAll + (size_t)e * DD * DD;
  int off = offs[e];
  int Me = offs[e + 1] - off;
  if (m0 >= Me) return;
  __shared__ ushort lA[2][128 * 32];
  __shared__ ushort lB[2][128 * 32];
  int tid = threadIdx.x;
  int l = tid & 63, wid = tid >> 6;
  int wm = wid >> 1, wn = wid & 1;
  fx4 zero = {0.f, 0.f, 0.f, 0.f};
  fx4 acc[4][4];
  #pragma unroll
  for (int mt = 0; mt < 4; ++mt)
    #pragma unroll
    for (int nt = 0; nt < 4; ++nt) acc[mt][nt] = zero;
  int sr = tid >> 2;
  int scg = (((l & 3) ^ ((l >> 2) & 3)) << 3);
  int dofs = wid * 512;
  int cr0 = m0 + sr;      if (cr0 > Me - 1) cr0 = Me - 1;
  int cr1 = m0 + sr + 64; if (cr1 > Me - 1) cr1 = Me - 1;
  size_t ar0, ar1;
  if (MODE == 0) { ar0 = (size_t)list[off + cr0]; ar1 = (size_t)list[off + cr1]; }
  else           { ar0 = (size_t)(off + cr0);     ar1 = (size_t)(off + cr1); }

#define ISSUE_MOE(BUF, KT)                                                       \
  do {                                                                           \
    GLOAD16(A  + ar0 * K + (KT) + scg,                    lA[BUF] + dofs);       \
    GLOAD16(A  + ar1 * K + (KT) + scg,                    lA[BUF] + 2048 + dofs);\
    GLOAD16(Bt + (size_t)(n0 + sr) * K + (KT) + scg,      lB[BUF] + dofs);       \
    GLOAD16(Bt + (size_t)(n0 + sr + 64) * K + (KT) + scg, lB[BUF] + 2048 + dofs);\
  } while (0)

#define COMP_MOE(BUF)                                                            \
  do {                                                                           \
    int kb = (l >> 4) << 4;                                                      \
    bfx8 bfr[4];                                                                 \
    _Pragma("unroll")                                                            \
    for (int nt = 0; nt < 4; ++nt) {                                             \
      int row = wn * 64 + nt * 16 + (l & 15);                                    \
      bfr[nt] = *(bfx8*)((char*)lB[BUF] + row * 64 + (kb ^ ((row & 3) << 4)));   \
    }                                                                            \
    _Pragma("unroll")                                                            \
    for (int mt = 0; mt < 4; ++mt) {                                             \
      int row = wm * 64 + mt * 16 + (l & 15);                                    \
      bfx8 af = *(bfx8*)((char*)lA[BUF] + row * 64 + (kb ^ ((row & 3) << 4)));   \
      _Pragma("unroll")                                                          \
      for (int nt = 0; nt < 4; ++nt)                                             \
        acc[mt][nt] = __builtin_amdgcn_mfma_f32_16x16x32_bf16(af, bfr[nt], acc[mt][nt], 0, 0, 0); \
    }                                                                            \
  } while (0)

  ISSUE_MOE(0, 0);
  for (int kt = 0; kt < K; kt += 64) {
    __syncthreads();
    if (kt + 32 < K) ISSUE_MOE(1, kt + 32);
    COMP_MOE(0);
    __syncthreads();
    if (kt + 64 < K) ISSUE_MOE(0, kt + 64);
    COMP_MOE(1);
  }
#undef ISSUE_MOE
#undef COMP_MOE

  #pragma unroll
  for (int mt = 0; mt < 4; ++mt)
    #pragma unroll
    for (int nt = 0; nt < 4; ++nt)
      #pragma unroll
      for (int r = 0; r < 4; ++r) {
        int rowt = wm * 64 + mt * 16 + ((l >> 4) << 2) + r;
        if (m0 + rowt < Me) {
          int col = n0 + wn * 64 + nt * 16 + (l & 15);
          float vv = acc[mt][nt][r];
          size_t idx = (size_t)(off + m0 + rowt) * N + col;
          if (MODE == 0) hb[idx] = f2bf(fmaxf(vv, 0.f));
          else           ob[idx] = f2bf(vv);
        }
      }
}

// ---------------- combine: out = psum + w1*o[inv1] + w2*o[inv2] (o in bf16) ----------------
__global__ __launch_bounds__(256) void k_combine(
    const float* __restrict__ psum, const ushort* __restrict__ ob,
    const int* __restrict__ inv, const float* __restrict__ w12,
    float* __restrict__ out) {
  int t = blockIdx.x;
  int d = threadIdx.x * 4;
  v4f a = *(const v4f*)(psum + (size_t)t * DD + d);
  ushort4 u1 = *(const ushort4*)(ob + (size_t)inv[2 * t] * DD + d);
  ushort4 u2 = *(const ushort4*)(ob + (size_t)inv[2 * t + 1] * DD + d);
  float w1 = w12[2 * t], w2 = w12[2 * t + 1];
  v4f r;
  r[0] = a[0] + w1 * b2f(u1.x) + w2 * b2f(u2.x);
  r[1] = a[1] + w1 * b2f(u1.y) + w2 * b2f(u2.y);
  r[2] = a[2] + w1 * b2f(u1.z) + w2 * b2f(u2.z);
  r[3] = a[3] + w1 * b2f(u1.w) + w2 * b2f(u2.w);
  *(v4f*)(out + (size_t)t * DD + d) = r;
}

// ---------------- aux loss: deterministic single-block reduce ----------------
__global__ __launch_bounds__(256) void k_aux(
    const float* __restrict__ probs, const int* __restrict__ sel,
    float* __restrict__ auxout) {
  int tid = threadIdx.x;
  float ps[8] = {}, cs[8] = {};
  for (int t = tid; t < NT; t += 256) {
    #pragma unroll
    for (int e = 0; e < 8; ++e) ps[e] += probs[t * 8 + e];
    int s = sel[t];
    cs[s >> 3] += 1.f; cs[s & 7] += 1.f;
  }
  __shared__ float red[4];
  __shared__ float tot[16];
  #pragma unroll
  for (int vv = 0; vv < 16; ++vv) {
    float s = (vv < 8) ? ps[vv] : cs[vv - 8];
    #pragma unroll
    for (int o = 32; o; o >>= 1) s += __shfl_down(s, o);
    __syncthreads();
    if ((tid & 63) == 0) red[tid >> 6] = s;
    __syncthreads();
    if (tid == 0) tot[vv] = red[0] + red[1] + red[2] + red[3];
  }
  __syncthreads();
  if (tid == 0) {
    float aux = 0.f;
    for (int e = 0; e < 8; ++e)
      aux += (tot[8 + e] * (1.f / NT)) * (tot[e] * (1.f / NT));
    auxout[0] = 8.f * aux;
  }
}

extern "C" void kernel_launch(void* const* d_in, const int* in_sizes, int n_in,
                              void* d_out, int out_size, void* d_ws, size_t ws_size,
                              hipStream_t stream) {
  (void)in_sizes; (void)n_in; (void)out_size; (void)ws_size;
  const float* x     = (const float*)d_in[0];
  const float* wpre  = (const float*)d_in[1];
  const float* wpost = (const float*)d_in[2];
  const float* Wq    = (const float*)d_in[3];
  const float* Wk    = (const float*)d_in[4];
  const float* Wv    = (const float*)d_in[5];
  const float* Wo    = (const float*)d_in[6];
  const float* gw    = (const float*)d_in[7];
  const float* W1    = (const float*)d_in[8];
  const float* W2    = (const float*)d_in[9];
  float* out = (float*)d_out;
  char* ws = (char*)d_ws;
  const size_t MB = 1ull << 20;
  // phase-overlaid workspace map (112MB + tail)
  ushort* preh  = (ushort*)(ws + 0 * MB);   // 8MB  -> aoh -> hb(16MB @0)
  ushort* prel  = (ushort*)(ws + 8 * MB);   // 8MB  -> aol
  ushort* qh    = (ushort*)(ws + 16 * MB);  // 8MB  -> postf (16MB @16)
  ushort* ql    = (ushort*)(ws + 24 * MB);  // 8MB
  ushort* kh    = (ushort*)(ws + 32 * MB);  // 8MB  -> postb (8MB @32)
  ushort* kl    = (ushort*)(ws + 40 * MB);  // 8MB  -> ob (16MB @40)
  ushort* vth   = (ushort*)(ws + 48 * MB);  // 8MB
  ushort* vtl   = (ushort*)(ws + 56 * MB);  // 8MB
  float*  psum  = (float*)(ws + 64 * MB);   // 16MB (live to end)
  ushort* Wt4h  = (ushort*)(ws + 80 * MB);  // 8MB  -> W1t (16MB @80)
  ushort* Wt4l  = (ushort*)(ws + 88 * MB);  // 8MB
  ushort* W2t   = (ushort*)(ws + 96 * MB);  // 16MB
  ushort* W1t   = (ushort*)(ws + 80 * MB);
  ushort* aoh   = preh;
  ushort* aol   = prel;
  float*  postf = (float*)(ws + 16 * MB);
  ushort* postb = (ushort*)(ws + 32 * MB);
  ushort* hb    = (ushort*)(ws + 0 * MB);
  ushort* ob    = (ushort*)(ws + 40 * MB);
  float*  probs = (float*)(ws + 112 * MB);
  int*    sel   = (int*)(ws + 112 * MB + (128u << 10));
  float*  w12   = (float*)(ws + 112 * MB + (160u << 10));
  int*    list  = (int*)(ws + 112 * MB + (192u << 10));
  int*    offs  = (int*)(ws + 112 * MB + (224u << 10));
  int*    inv   = (int*)(ws + 112 * MB + (256u << 10));

  // pre-norm -> fp16 hi/lo (x64)
  k_rmsnorm<<<NT, 256, 0, stream>>>(x, wpre, nullptr, nullptr, preh, prel);
  // weight transpose+split for Wq/Wk/Wv/Wo
  k_wsplit<<<dim3(32, 32, 4), 256, 0, stream>>>(Wq, Wk, Wv, Wo, Wt4h, Wt4l);
  // QKV via split-fp16 MFMA (XCD-chunked flat grid, 768 blocks)
  k_gemm_sp<0><<<768, 256, 0, stream>>>(
      preh, prel, Wt4h, Wt4l, nullptr, nullptr, qh, ql, kh, kl, vth, vtl);
  // MFMA flash attention (R17 config) -> hi/lo fp16
  k_attn<<<512, 512, 0, stream>>>(qh, ql, kh, kl, vth, vtl, aoh, aol);
  // Wo + residual -> post_sum (XCD-chunked flat grid, 256 blocks)
  k_gemm_sp<1><<<256, 256, 0, stream>>>(
      aoh, aol, Wt4h + (size_t)3 * DD * DD, Wt4l + (size_t)3 * DD * DD,
      psum, x, nullptr, nullptr, nullptr, nullptr, nullptr, nullptr);
  // post-norm: fp32 (gating) + bf16 (MoE A operand)
  k_rmsnorm<<<NT, 256, 0, stream>>>(psum, wpost, postf, postb, nullptr, nullptr);
  // expert weights -> bf16 transposed (both W1 and W2 in one dispatch)
  k_tcast<<<dim3(32, 32, 16), 256, 0, stream>>>(W1, W2, W1t, DD, DD);
  // gating (fp32, exact top-k path)
  k_gate<<<NT / 4, 256, 0, stream>>>(postf, gw, w12, probs, sel);
  // routing
  k_count<<<1, 256, 0, stream>>>(sel, offs);
  k_place<<<8, 256, 0, stream>>>(sel, offs, list, inv);
  // sparse MoE: XCD-chunked flat grids (2048 blocks each; 1 expert per XCD)
  k_moe_gemm<0><<<2048, 256, 0, stream>>>(
      postb, W1t, hb, nullptr, list, offs, DD, DD);
  k_moe_gemm<1><<<2048, 256, 0, stream>>>(
      hb, W2t, nullptr, ob, list, offs, DD, DD);
  // combine + aux
  k_combine<<<NT, 256, 0, stream>>>(psum, ob, inv, w12, out);
  k_aux<<<1, 256, 0, stream>>>(probs, sel, out + 4194304);
}